// Round 4
// baseline (920.940 us; speedup 1.0000x reference)
//
#include <hip/hip_runtime.h>
#include <math.h>

#define IN_DIM 128
#define HID 64
#define OUTD 32
#define BSH 7           // log2 nodes per bucket
#define BSZ (1 << BSH)  // 128 nodes per bucket

// Per-graph pointer bundle for kernels fused across both graphs (blockIdx.y).
struct GB {
    const int* src; const int* dst;
    int* bcnt; int* boff; int* bcur;
    int2* pairs;
    int* rowptr; int* csr_src;
    float* dinv;
    double* st; float* mr; float* og;
};

// ---------------- stage 1: bucket histogram (dst >> BSH) ----------------
__global__ void k_bucket_count(GB g0, GB g1, int e, int nb) {
    const GB& g = blockIdx.y ? g1 : g0;
    __shared__ int hist[512];
    int tid = threadIdx.x;
    for (int i = tid; i < nb; i += 256) hist[i] = 0;
    __syncthreads();
    size_t base = (size_t)blockIdx.x * 4096;
    for (int k = 0; k < 16; ++k) {
        size_t idx = base + (size_t)k * 256 + tid;
        if (idx < (size_t)e) atomicAdd(&hist[g.dst[idx] >> BSH], 1);
    }
    __syncthreads();
    for (int i = tid; i < nb; i += 256)
        if (hist[i]) atomicAdd(&g.bcnt[i], hist[i]);
}

// ---------------- stage 2: scan bucket counts (nb <= 1024) ----------------
__global__ void k_scan_buckets(GB g0, GB g1, int nb) {
    const GB& g = blockIdx.y ? g1 : g0;
    __shared__ int ls[1024];
    int tid = threadIdx.x;
    int v = (tid < nb) ? g.bcnt[tid] : 0;
    ls[tid] = v;
    __syncthreads();
    for (int off = 1; off < 1024; off <<= 1) {
        int u = (tid >= off) ? ls[tid - off] : 0;
        __syncthreads();
        ls[tid] += u;
        __syncthreads();
    }
    if (tid < nb) { int ex = ls[tid] - v; g.boff[tid] = ex; g.bcur[tid] = ex; }
    if (tid < 64) g.st[tid] = 0.0;
}

// ---------------- stage 3: partition edges into bucket regions ----------------
__global__ void k_partition(GB g0, GB g1, int e) {
    const GB& g = blockIdx.y ? g1 : g0;
    int i = blockIdx.x * 256 + threadIdx.x;
    if (i < e) {
        int s = g.src[i], d = g.dst[i];
        int pos = atomicAdd(&g.bcur[d >> BSH], 1);
        g.pairs[pos] = make_int2(s, d);
    }
}

// ---------------- stage 4: per-bucket local CSR (LDS cursors, no global atomics) ----------------
__global__ void k_local_csr(GB g0, GB g1, int n, int e) {
    const GB& g = blockIdx.y ? g1 : g0;
    __shared__ int ldeg[BSZ], lrow[BSZ];
    int tid = threadIdx.x;
    int b = blockIdx.x;
    int node0 = b << BSH;
    int lo = g.boff[b], hi = lo + g.bcnt[b];
    if (tid < BSZ) ldeg[tid] = 0;
    __syncthreads();
    for (int j = lo + tid; j < hi; j += 256) {
        int2 p = g.pairs[j];
        atomicAdd(&ldeg[p.y - node0], 1);
    }
    __syncthreads();
    if (tid < BSZ) lrow[tid] = ldeg[tid];
    __syncthreads();
    for (int off = 1; off < BSZ; off <<= 1) {
        int u = (tid < BSZ && tid >= off) ? lrow[tid - off] : 0;
        __syncthreads();
        if (tid < BSZ) lrow[tid] += u;
        __syncthreads();
    }
    int node = node0 + tid;
    if (tid < BSZ && node < n) {
        int ex = lrow[tid] - ldeg[tid];          // exclusive scan value
        g.rowptr[node] = lo + ex;
        g.dinv[node] = rsqrtf((float)(ldeg[tid] + 1));  // +1 self-loop
    }
    __syncthreads();
    if (tid < BSZ) lrow[tid] -= ldeg[tid];       // convert to cursors
    __syncthreads();
    for (int j = lo + tid; j < hi; j += 256) {
        int2 p = g.pairs[j];
        int pos = lo + atomicAdd(&lrow[p.y - node0], 1);  // LDS atomic
        g.csr_src[pos] = p.x;
    }
    if (b == 0 && tid == 0) g.rowptr[n] = e;
}

// ---------------- dense matmul: Hs[n,D] = (X[n,K] @ W[K,D]) * dinv ----------------
template<int K, int D>
__global__ void k_matmul(const float* __restrict__ X, const float* __restrict__ W,
                         const float* __restrict__ dinv, float* __restrict__ H, int n) {
    constexpr int NPB = 256 / D;
    __shared__ float xs[NPB][K];
    int node0 = blockIdx.x * NPB;
    int lid = threadIdx.x;
    for (int idx = lid; idx < NPB * K; idx += 256) {
        int nn = idx / K, kk = idx % K;
        int gn = node0 + nn;
        xs[nn][kk] = (gn < n) ? X[(size_t)gn * K + kk] : 0.0f;
    }
    __syncthreads();
    int g = lid / D, f = lid % D;
    int node = node0 + g;
    if (node >= n) return;
    float acc = 0.0f;
#pragma unroll
    for (int k = 0; k < K; ++k) acc = fmaf(xs[g][k], W[k * D + f], acc);
    H[(size_t)node * D + f] = acc * dinv[node];
}

// ---------------- layer-1 gather fused with layer-2 matmul ----------------
// agg = relu(dinv*(Hs[d]+sum Hs[s]) + b1) lives only in LDS; H2 = (agg@W2)*dinv
__global__ void k_gather_fuse(const int* __restrict__ rowptr, const int* __restrict__ csr_src,
                              const float* __restrict__ Hs, const float* __restrict__ dinv,
                              const float* __restrict__ b1, const float* __restrict__ W2,
                              float* __restrict__ H2, int n) {
    __shared__ float sh[4][HID];
    int tid = threadIdx.x;
    int f = tid & 63, gi = tid >> 6;
    int node = blockIdx.x * 4 + gi;
    float acc = 0.0f;
    if (node < n) {
        acc = Hs[(size_t)node * HID + f];  // self-loop
        int lo = rowptr[node], hi = rowptr[node + 1];
        for (int j = lo; j < hi; ++j) acc += Hs[(size_t)csr_src[j] * HID + f];
        acc = fmaxf(dinv[node] * acc + b1[f], 0.0f);
    }
    sh[gi][f] = acc;
    __syncthreads();
    if (tid < 128) {
        int g2 = tid >> 5, f2 = tid & 31;
        int node2 = blockIdx.x * 4 + g2;
        if (node2 < n) {
            float a2 = 0.0f;
#pragma unroll
            for (int k = 0; k < HID; ++k) a2 = fmaf(sh[g2][k], W2[k * OUTD + f2], a2);
            H2[(size_t)node2 * OUTD + f2] = a2 * dinv[node2];
        }
    }
}

// ---------------- layer-2 gather ----------------
template<int D>
__global__ void k_gather(const int* __restrict__ rowptr, const int* __restrict__ csr_src,
                         const float* __restrict__ Hs, const float* __restrict__ dinv,
                         float* __restrict__ out, int n) {
    constexpr int NPB = 256 / D;
    int tid = threadIdx.x;
    int f = tid & (D - 1);
    int node = blockIdx.x * NPB + tid / D;
    if (node >= n) return;
    int lo = rowptr[node], hi = rowptr[node + 1];
    float acc = Hs[(size_t)node * D + f];
    for (int j = lo; j < hi; ++j) acc += Hs[(size_t)csr_src[j] * D + f];
    out[(size_t)node * D + f] = dinv[node] * acc;
}

// ---------------- column z-score ----------------

__global__ void k_stats(GB g0, GB g1, int n) {
    const GB& g = blockIdx.y ? g1 : g0;
    int tid = threadIdx.x;
    int c = tid & 31;
    double s = 0.0, q = 0.0;
    long total = (long)n * OUTD;
    for (long t = (long)blockIdx.x * blockDim.x + tid; t < total;
         t += (long)gridDim.x * blockDim.x) {
        double v = (double)g.og[t];
        s += v; q += v * v;
    }
    __shared__ double ls[256], lq[256];
    ls[tid] = s; lq[tid] = q;
    __syncthreads();
    if (tid < 32) {
        for (int j = 32; j < 256; j += 32) { s += ls[tid + j]; q += lq[tid + j]; }
        atomicAdd(&g.st[c], s);
        atomicAdd(&g.st[c + 32], q);
    }
}

__global__ void k_finalize(GB g0, GB g1, int n) {
    const GB& g = blockIdx.y ? g1 : g0;
    int c = threadIdx.x;
    if (c < 32) {
        double sum = g.st[c], sq = g.st[c + 32];
        double mean = sum / (double)n;
        double var = (sq - sum * sum / (double)n) / (double)(n - 1);
        g.mr[c] = (float)mean;
        g.mr[c + 32] = (float)(1.0 / sqrt(var));
    }
}

__global__ void k_transform(GB g0, GB g1, int n) {
    const GB& g = blockIdx.y ? g1 : g0;
    int t = blockIdx.x * 256 + threadIdx.x;
    if (t < n * OUTD) {
        int c = t & 31;
        g.og[t] = (g.og[t] - g.mr[c]) * g.mr[c + 32];
    }
}

// ---------------- launch ----------------

extern "C" void kernel_launch(void* const* d_in, const int* in_sizes, int n_in,
                              void* d_out, int out_size, void* d_ws, size_t ws_size,
                              hipStream_t stream) {
    const float* x1 = (const float*)d_in[0];
    const int*   ei1 = (const int*)d_in[1];
    const float* x2 = (const float*)d_in[2];
    const int*   ei2 = (const int*)d_in[3];
    const float* W1 = (const float*)d_in[4];
    const float* b1 = (const float*)d_in[5];
    const float* W2 = (const float*)d_in[6];
    const float* b2 = (const float*)d_in[7];
    (void)b2;  // column-constant shift cancels exactly in the z-score
    (void)n_in; (void)out_size; (void)ws_size;

    int n = in_sizes[0] / IN_DIM;   // 50000
    int e = in_sizes[1] / 2;        // 800000
    float* out = (float*)d_out;
    int nb  = (n + BSZ - 1) >> BSH; // 391 buckets
    int nbc = (e + 4095) / 4096;    // 196 histogram blocks
    int nbe = (e + 255) / 256;      // 3125 partition blocks

    char* ws = (char*)d_ws;
    size_t off = 0;
    auto alloc = [&](size_t bytes) {
        void* p = ws + off;
        off = (off + bytes + 255) & ~(size_t)255;
        return p;
    };
    int*    bcnt_base = (int*)alloc((size_t)2 * nb * 4);
    int*    boff_base = (int*)alloc((size_t)2 * nb * 4);
    int*    bcur_base = (int*)alloc((size_t)2 * nb * 4);
    double* st_base   = (double*)alloc(2 * 64 * 8);

    GB G[2];
    for (int g = 0; g < 2; ++g) {
        const int* ei = g ? ei2 : ei1;
        G[g].src = ei;
        G[g].dst = ei + e;
        G[g].bcnt = bcnt_base + (size_t)g * nb;
        G[g].boff = boff_base + (size_t)g * nb;
        G[g].bcur = bcur_base + (size_t)g * nb;
        G[g].st   = st_base + (size_t)g * 64;
        G[g].rowptr  = (int*)alloc(((size_t)n + 1) * 4);
        G[g].csr_src = (int*)alloc((size_t)e * 4);
        G[g].dinv    = (float*)alloc((size_t)n * 4);
        G[g].mr      = (float*)alloc(64 * 4);
        G[g].og      = out + (size_t)g * n * OUTD;
    }
    // union region: pairs (build phase) aliases hs+h2 (compute phase)
    size_t pairs_bytes = (size_t)2 * e * 8;
    size_t dense_bytes = (size_t)n * HID * 4 + (size_t)n * OUTD * 4;
    char* uni = (char*)alloc(pairs_bytes > dense_bytes ? pairs_bytes : dense_bytes);
    G[0].pairs = (int2*)uni;
    G[1].pairs = G[0].pairs + e;
    float* hs = (float*)uni;
    float* h2 = (float*)(uni + (size_t)n * HID * 4);

    hipMemsetAsync(bcnt_base, 0, (size_t)2 * nb * 4, stream);

    // bucketed CSR build, both graphs fused
    k_bucket_count<<<dim3(nbc, 2), 256, 0, stream>>>(G[0], G[1], e, nb);
    k_scan_buckets<<<dim3(1, 2), 1024, 0, stream>>>(G[0], G[1], nb);
    k_partition<<<dim3(nbe, 2), 256, 0, stream>>>(G[0], G[1], e);
    k_local_csr<<<dim3(nb, 2), 256, 0, stream>>>(G[0], G[1], n, e);

    // per-graph compute (hs/h2 shared across graphs -> serialize)
    for (int g = 0; g < 2; ++g) {
        const float* x = g ? x2 : x1;
        k_matmul<IN_DIM, HID><<<(n + 3) / 4, 256, 0, stream>>>(x, W1, G[g].dinv, hs, n);
        k_gather_fuse<<<(n + 3) / 4, 256, 0, stream>>>(G[g].rowptr, G[g].csr_src, hs,
                                                       G[g].dinv, b1, W2, h2, n);
        k_gather<OUTD><<<(n + 7) / 8, 256, 0, stream>>>(G[g].rowptr, G[g].csr_src, h2,
                                                        G[g].dinv, G[g].og, n);
    }

    // fused z-score for both graphs (st zeroed in k_scan_buckets)
    k_stats<<<dim3(512, 2), 256, 0, stream>>>(G[0], G[1], n);
    k_finalize<<<dim3(1, 2), 32, 0, stream>>>(G[0], G[1], n);
    k_transform<<<dim3((n * OUTD + 255) / 256, 2), 256, 0, stream>>>(G[0], G[1], n);
}

// Round 5
// 433.242 us; speedup vs baseline: 2.1257x; 2.1257x over previous
//
#include <hip/hip_runtime.h>
#include <math.h>

#define IN_DIM 128
#define HID 64
#define OUTD 32
#define BSH 8            // log2 nodes per bucket
#define BSZ 256          // nodes per bucket == threads per local-CSR block
#define EPB 4096         // edges per histogram/partition block

// Per-graph pointer bundle for kernels fused across both graphs (blockIdx.y).
struct GB {
    const int* src; const int* dst;
    int* bh;               // [nbh][nb]: per-block bucket counts -> excl-in-bucket offsets
    int* btot;             // [nb] bucket totals
    int* boff;             // [nb] bucket base offsets (exclusive scan of btot)
    unsigned int* pairs;   // bucket-partitioned edges: src | (local_dst << 24)
    int* rowptr; int* csr_src;
    float* dinv;
    double* st; float* mr; float* og;
};

// ---------------- stage 1: per-block LDS histogram, dense output (no global atomics) ----------------
__global__ void k_hist(GB g0, GB g1, int e, int nb) {
    const GB& g = blockIdx.y ? g1 : g0;
    __shared__ int hist[512];           // nb <= 512
    int tid = threadIdx.x;
    for (int i = tid; i < nb; i += 256) hist[i] = 0;
    __syncthreads();
    int base = blockIdx.x * EPB;
#pragma unroll
    for (int k = 0; k < EPB / 256; ++k) {
        int idx = base + k * 256 + tid;
        if (idx < e) atomicAdd(&hist[g.dst[idx] >> BSH], 1);  // LDS atomic
    }
    __syncthreads();
    int* row = g.bh + (size_t)blockIdx.x * nb;
    for (int i = tid; i < nb; i += 256) row[i] = hist[i];     // coalesced dense write
}

// ---------------- stage 2: per-bucket column scan (one block per bucket) ----------------
// bh[blk][b] -> exclusive prefix within bucket b; btot[b] = total.
__global__ void k_colscan(GB g0, GB g1, int nb, int nbh) {
    const GB& g = blockIdx.y ? g1 : g0;
    __shared__ int ls[256];             // nbh <= 256
    int tid = threadIdx.x;
    int b = blockIdx.x;
    int v = (tid < nbh) ? g.bh[(size_t)tid * nb + b] : 0;
    ls[tid] = v;
    __syncthreads();
    for (int off = 1; off < 256; off <<= 1) {
        int u = (tid >= off) ? ls[tid - off] : 0;
        __syncthreads();
        ls[tid] += u;
        __syncthreads();
    }
    if (tid < nbh) g.bh[(size_t)tid * nb + b] = ls[tid] - v;  // exclusive
    if (tid == 255) g.btot[b] = ls[255];
}

// ---------------- stage 3: cross-bucket scan (nb <= 1024) + zero stats ----------------
__global__ void k_scan_btot(GB g0, GB g1, int nb) {
    const GB& g = blockIdx.y ? g1 : g0;
    __shared__ int ls[1024];
    int tid = threadIdx.x;
    int v = (tid < nb) ? g.btot[tid] : 0;
    ls[tid] = v;
    __syncthreads();
    for (int off = 1; off < 1024; off <<= 1) {
        int u = (tid >= off) ? ls[tid - off] : 0;
        __syncthreads();
        ls[tid] += u;
        __syncthreads();
    }
    if (tid < nb) g.boff[tid] = ls[tid] - v;
    if (tid < 64) g.st[tid] = 0.0;
}

// ---------------- stage 4: partition edges (LDS cursors only) ----------------
__global__ void k_part2(GB g0, GB g1, int e, int nb) {
    const GB& g = blockIdx.y ? g1 : g0;
    __shared__ int lcur[512];
    int tid = threadIdx.x;
    const int* row = g.bh + (size_t)blockIdx.x * nb;
    for (int i = tid; i < nb; i += 256) lcur[i] = g.boff[i] + row[i];
    __syncthreads();
    int base = blockIdx.x * EPB;
#pragma unroll
    for (int k = 0; k < EPB / 256; ++k) {
        int idx = base + k * 256 + tid;
        if (idx < e) {
            int s = g.src[idx], d = g.dst[idx];
            int pos = atomicAdd(&lcur[d >> BSH], 1);          // LDS atomic
            g.pairs[pos] = (unsigned int)s | ((unsigned int)(d & (BSZ - 1)) << 24);
        }
    }
}

// ---------------- stage 5: per-bucket local CSR (LDS cursors, 16KB write window) ----------------
__global__ void k_local_csr(GB g0, GB g1, int n, int e) {
    const GB& g = blockIdx.y ? g1 : g0;
    __shared__ int ldeg[BSZ], lrow[BSZ];
    int tid = threadIdx.x;
    int b = blockIdx.x;
    int node0 = b << BSH;
    int lo = g.boff[b], hi = lo + g.btot[b];
    ldeg[tid] = 0;
    __syncthreads();
    for (int j = lo + tid; j < hi; j += 256)
        atomicAdd(&ldeg[g.pairs[j] >> 24], 1);
    __syncthreads();
    int d = ldeg[tid];
    lrow[tid] = d;
    __syncthreads();
    for (int off = 1; off < BSZ; off <<= 1) {
        int u = (tid >= off) ? lrow[tid - off] : 0;
        __syncthreads();
        lrow[tid] += u;
        __syncthreads();
    }
    int node = node0 + tid;
    if (node < n) {
        g.rowptr[node] = lo + lrow[tid] - d;
        g.dinv[node] = rsqrtf((float)(d + 1));   // +1 = self-loop
    }
    lrow[tid] = lo + lrow[tid] - d;              // absolute cursor (own index only)
    __syncthreads();
    for (int j = lo + tid; j < hi; j += 256) {
        unsigned int w = g.pairs[j];
        int pos = atomicAdd(&lrow[w >> 24], 1);  // LDS atomic
        g.csr_src[pos] = (int)(w & 0xFFFFFFu);
    }
    if (b == 0 && tid == 0) g.rowptr[n] = e;
}

// ---------------- dense matmul: Hs[n,D] = (X[n,K] @ W[K,D]) * dinv ----------------
template<int K, int D>
__global__ void k_matmul(const float* __restrict__ X, const float* __restrict__ W,
                         const float* __restrict__ dinv, float* __restrict__ H, int n) {
    constexpr int NPB = 256 / D;
    __shared__ float xs[NPB][K];
    int node0 = blockIdx.x * NPB;
    int lid = threadIdx.x;
    for (int idx = lid; idx < NPB * K; idx += 256) {
        int nn = idx / K, kk = idx % K;
        int gn = node0 + nn;
        xs[nn][kk] = (gn < n) ? X[(size_t)gn * K + kk] : 0.0f;
    }
    __syncthreads();
    int g = lid / D, f = lid % D;
    int node = node0 + g;
    if (node >= n) return;
    float acc = 0.0f;
#pragma unroll
    for (int k = 0; k < K; ++k) acc = fmaf(xs[g][k], W[k * D + f], acc);
    H[(size_t)node * D + f] = acc * dinv[node];
}

// ---------------- layer-1 gather fused with layer-2 matmul ----------------
__global__ void k_gather_fuse(const int* __restrict__ rowptr, const int* __restrict__ csr_src,
                              const float* __restrict__ Hs, const float* __restrict__ dinv,
                              const float* __restrict__ b1, const float* __restrict__ W2,
                              float* __restrict__ H2, int n) {
    __shared__ float sh[4][HID];
    int tid = threadIdx.x;
    int f = tid & 63, gi = tid >> 6;
    int node = blockIdx.x * 4 + gi;
    float acc = 0.0f;
    if (node < n) {
        acc = Hs[(size_t)node * HID + f];  // self-loop
        int lo = rowptr[node], hi = rowptr[node + 1];
        for (int j = lo; j < hi; ++j) acc += Hs[(size_t)csr_src[j] * HID + f];
        acc = fmaxf(dinv[node] * acc + b1[f], 0.0f);
    }
    sh[gi][f] = acc;
    __syncthreads();
    if (tid < 128) {
        int g2 = tid >> 5, f2 = tid & 31;
        int node2 = blockIdx.x * 4 + g2;
        if (node2 < n) {
            float a2 = 0.0f;
#pragma unroll
            for (int k = 0; k < HID; ++k) a2 = fmaf(sh[g2][k], W2[k * OUTD + f2], a2);
            H2[(size_t)node2 * OUTD + f2] = a2 * dinv[node2];
        }
    }
}

// ---------------- layer-2 gather ----------------
template<int D>
__global__ void k_gather(const int* __restrict__ rowptr, const int* __restrict__ csr_src,
                         const float* __restrict__ Hs, const float* __restrict__ dinv,
                         float* __restrict__ out, int n) {
    constexpr int NPB = 256 / D;
    int tid = threadIdx.x;
    int f = tid & (D - 1);
    int node = blockIdx.x * NPB + tid / D;
    if (node >= n) return;
    int lo = rowptr[node], hi = rowptr[node + 1];
    float acc = Hs[(size_t)node * D + f];
    for (int j = lo; j < hi; ++j) acc += Hs[(size_t)csr_src[j] * D + f];
    out[(size_t)node * D + f] = dinv[node] * acc;
}

// ---------------- column z-score ----------------

__global__ void k_stats(GB g0, GB g1, int n) {
    const GB& g = blockIdx.y ? g1 : g0;
    int tid = threadIdx.x;
    int c = tid & 31;
    double s = 0.0, q = 0.0;
    long total = (long)n * OUTD;
    for (long t = (long)blockIdx.x * blockDim.x + tid; t < total;
         t += (long)gridDim.x * blockDim.x) {
        double v = (double)g.og[t];
        s += v; q += v * v;
    }
    __shared__ double ls[256], lq[256];
    ls[tid] = s; lq[tid] = q;
    __syncthreads();
    if (tid < 32) {
        for (int j = 32; j < 256; j += 32) { s += ls[tid + j]; q += lq[tid + j]; }
        atomicAdd(&g.st[c], s);
        atomicAdd(&g.st[c + 32], q);
    }
}

__global__ void k_finalize(GB g0, GB g1, int n) {
    const GB& g = blockIdx.y ? g1 : g0;
    int c = threadIdx.x;
    if (c < 32) {
        double sum = g.st[c], sq = g.st[c + 32];
        double mean = sum / (double)n;
        double var = (sq - sum * sum / (double)n) / (double)(n - 1);
        g.mr[c] = (float)mean;
        g.mr[c + 32] = (float)(1.0 / sqrt(var));
    }
}

__global__ void k_transform(GB g0, GB g1, int n) {
    const GB& g = blockIdx.y ? g1 : g0;
    int t = blockIdx.x * 256 + threadIdx.x;
    if (t < n * OUTD) {
        int c = t & 31;
        g.og[t] = (g.og[t] - g.mr[c]) * g.mr[c + 32];
    }
}

// ---------------- launch ----------------

extern "C" void kernel_launch(void* const* d_in, const int* in_sizes, int n_in,
                              void* d_out, int out_size, void* d_ws, size_t ws_size,
                              hipStream_t stream) {
    const float* x1 = (const float*)d_in[0];
    const int*   ei1 = (const int*)d_in[1];
    const float* x2 = (const float*)d_in[2];
    const int*   ei2 = (const int*)d_in[3];
    const float* W1 = (const float*)d_in[4];
    const float* b1 = (const float*)d_in[5];
    const float* W2 = (const float*)d_in[6];
    const float* b2 = (const float*)d_in[7];
    (void)b2;  // column-constant shift cancels exactly in the z-score
    (void)n_in; (void)out_size; (void)ws_size;

    int n = in_sizes[0] / IN_DIM;    // 50000
    int e = in_sizes[1] / 2;         // 800000
    float* out = (float*)d_out;
    int nb  = (n + BSZ - 1) >> BSH;  // 196 buckets
    int nbh = (e + EPB - 1) / EPB;   // 196 edge blocks

    char* ws = (char*)d_ws;
    size_t off = 0;
    auto alloc = [&](size_t bytes) {
        void* p = ws + off;
        off = (off + bytes + 255) & ~(size_t)255;
        return p;
    };
    int*    bh_base   = (int*)alloc((size_t)2 * nbh * nb * 4);
    int*    btot_base = (int*)alloc((size_t)2 * nb * 4);
    int*    boff_base = (int*)alloc((size_t)2 * nb * 4);
    double* st_base   = (double*)alloc(2 * 64 * 8);

    GB G[2];
    for (int g = 0; g < 2; ++g) {
        const int* ei = g ? ei2 : ei1;
        G[g].src  = ei;
        G[g].dst  = ei + e;
        G[g].bh   = bh_base + (size_t)g * nbh * nb;
        G[g].btot = btot_base + (size_t)g * nb;
        G[g].boff = boff_base + (size_t)g * nb;
        G[g].st   = st_base + (size_t)g * 64;
        G[g].rowptr  = (int*)alloc(((size_t)n + 1) * 4);
        G[g].csr_src = (int*)alloc((size_t)e * 4);
        G[g].dinv    = (float*)alloc((size_t)n * 4);
        G[g].mr      = (float*)alloc(64 * 4);
        G[g].og      = out + (size_t)g * n * OUTD;
    }
    // union region: pairs (build phase) aliases hs+h2 (compute phase)
    size_t pairs_bytes = (size_t)2 * e * 4;
    size_t dense_bytes = (size_t)n * HID * 4 + (size_t)n * OUTD * 4;
    char* uni = (char*)alloc(pairs_bytes > dense_bytes ? pairs_bytes : dense_bytes);
    G[0].pairs = (unsigned int*)uni;
    G[1].pairs = G[0].pairs + e;
    float* hs = (float*)uni;
    float* h2 = (float*)(uni + (size_t)n * HID * 4);

    // atomic-free bucketed CSR build, both graphs fused (no memsets needed)
    k_hist<<<dim3(nbh, 2), 256, 0, stream>>>(G[0], G[1], e, nb);
    k_colscan<<<dim3(nb, 2), 256, 0, stream>>>(G[0], G[1], nb, nbh);
    k_scan_btot<<<dim3(1, 2), 1024, 0, stream>>>(G[0], G[1], nb);
    k_part2<<<dim3(nbh, 2), 256, 0, stream>>>(G[0], G[1], e, nb);
    k_local_csr<<<dim3(nb, 2), BSZ, 0, stream>>>(G[0], G[1], n, e);

    // per-graph compute (hs/h2 shared across graphs -> serialize)
    for (int g = 0; g < 2; ++g) {
        const float* x = g ? x2 : x1;
        k_matmul<IN_DIM, HID><<<(n + 3) / 4, 256, 0, stream>>>(x, W1, G[g].dinv, hs, n);
        k_gather_fuse<<<(n + 3) / 4, 256, 0, stream>>>(G[g].rowptr, G[g].csr_src, hs,
                                                       G[g].dinv, b1, W2, h2, n);
        k_gather<OUTD><<<(n + 7) / 8, 256, 0, stream>>>(G[g].rowptr, G[g].csr_src, h2,
                                                        G[g].dinv, G[g].og, n);
    }

    // fused z-score for both graphs (st zeroed in k_scan_btot)
    k_stats<<<dim3(512, 2), 256, 0, stream>>>(G[0], G[1], n);
    k_finalize<<<dim3(1, 2), 32, 0, stream>>>(G[0], G[1], n);
    k_transform<<<dim3((n * OUTD + 255) / 256, 2), 256, 0, stream>>>(G[0], G[1], n);
}

// Round 6
// 349.871 us; speedup vs baseline: 2.6322x; 1.2383x over previous
//
#include <hip/hip_runtime.h>
#include <hip/hip_fp16.h>
#include <math.h>

#define IN_DIM 128
#define HID 64
#define OUTD 32
#define BSH 8            // log2 nodes per bucket
#define BSZ 256          // nodes per bucket == threads per local-CSR block
#define EPB 4096         // edges per histogram/partition block

// Per-graph pointer bundle for kernels fused across both graphs (blockIdx.y).
struct GB {
    const int* src; const int* dst;
    int* bh;               // [nbh][nb]: per-block bucket counts -> excl-in-bucket offsets
    int* btot;             // [nb] bucket totals
    int* boff;             // [nb] bucket base offsets (exclusive scan of btot)
    unsigned int* pairs;   // bucket-partitioned edges: src | (local_dst << 24)
    int* rowptr; int* csr_src;
    float* dinv;
    double* st; float* mr; float* og;
};

// ---------------- stage 1: per-block LDS histogram, dense output ----------------
__global__ void k_hist(GB g0, GB g1, int e, int nb) {
    const GB& g = blockIdx.y ? g1 : g0;
    __shared__ int hist[512];
    int tid = threadIdx.x;
    for (int i = tid; i < nb; i += 256) hist[i] = 0;
    __syncthreads();
    int base = blockIdx.x * EPB;
#pragma unroll
    for (int k = 0; k < EPB / 256; ++k) {
        int idx = base + k * 256 + tid;
        if (idx < e) atomicAdd(&hist[g.dst[idx] >> BSH], 1);  // LDS atomic
    }
    __syncthreads();
    int* row = g.bh + (size_t)blockIdx.x * nb;
    for (int i = tid; i < nb; i += 256) row[i] = hist[i];
}

// ---------------- stage 2: per-bucket column scan ----------------
__global__ void k_colscan(GB g0, GB g1, int nb, int nbh) {
    const GB& g = blockIdx.y ? g1 : g0;
    __shared__ int ls[256];
    int tid = threadIdx.x;
    int b = blockIdx.x;
    int v = (tid < nbh) ? g.bh[(size_t)tid * nb + b] : 0;
    ls[tid] = v;
    __syncthreads();
    for (int off = 1; off < 256; off <<= 1) {
        int u = (tid >= off) ? ls[tid - off] : 0;
        __syncthreads();
        ls[tid] += u;
        __syncthreads();
    }
    if (tid < nbh) g.bh[(size_t)tid * nb + b] = ls[tid] - v;
    if (tid == 255) g.btot[b] = ls[255];
}

// ---------------- stage 3: cross-bucket scan + zero stats ----------------
__global__ void k_scan_btot(GB g0, GB g1, int nb) {
    const GB& g = blockIdx.y ? g1 : g0;
    __shared__ int ls[1024];
    int tid = threadIdx.x;
    int v = (tid < nb) ? g.btot[tid] : 0;
    ls[tid] = v;
    __syncthreads();
    for (int off = 1; off < 1024; off <<= 1) {
        int u = (tid >= off) ? ls[tid - off] : 0;
        __syncthreads();
        ls[tid] += u;
        __syncthreads();
    }
    if (tid < nb) g.boff[tid] = ls[tid] - v;
    if (tid < 64) g.st[tid] = 0.0;
}

// ---------------- stage 4: partition edges (LDS cursors only) ----------------
__global__ void k_part2(GB g0, GB g1, int e, int nb) {
    const GB& g = blockIdx.y ? g1 : g0;
    __shared__ int lcur[512];
    int tid = threadIdx.x;
    const int* row = g.bh + (size_t)blockIdx.x * nb;
    for (int i = tid; i < nb; i += 256) lcur[i] = g.boff[i] + row[i];
    __syncthreads();
    int base = blockIdx.x * EPB;
#pragma unroll
    for (int k = 0; k < EPB / 256; ++k) {
        int idx = base + k * 256 + tid;
        if (idx < e) {
            int s = g.src[idx], d = g.dst[idx];
            int pos = atomicAdd(&lcur[d >> BSH], 1);          // LDS atomic
            g.pairs[pos] = (unsigned int)s | ((unsigned int)(d & (BSZ - 1)) << 24);
        }
    }
}

// ---------------- stage 5: per-bucket local CSR ----------------
__global__ void k_local_csr(GB g0, GB g1, int n, int e) {
    const GB& g = blockIdx.y ? g1 : g0;
    __shared__ int ldeg[BSZ], lrow[BSZ];
    int tid = threadIdx.x;
    int b = blockIdx.x;
    int node0 = b << BSH;
    int lo = g.boff[b], hi = lo + g.btot[b];
    ldeg[tid] = 0;
    __syncthreads();
    for (int j = lo + tid; j < hi; j += 256)
        atomicAdd(&ldeg[g.pairs[j] >> 24], 1);
    __syncthreads();
    int d = ldeg[tid];
    lrow[tid] = d;
    __syncthreads();
    for (int off = 1; off < BSZ; off <<= 1) {
        int u = (tid >= off) ? lrow[tid - off] : 0;
        __syncthreads();
        lrow[tid] += u;
        __syncthreads();
    }
    int node = node0 + tid;
    if (node < n) {
        g.rowptr[node] = lo + lrow[tid] - d;
        g.dinv[node] = rsqrtf((float)(d + 1));   // +1 = self-loop
    }
    lrow[tid] = lo + lrow[tid] - d;
    __syncthreads();
    for (int j = lo + tid; j < hi; j += 256) {
        unsigned int w = g.pairs[j];
        int pos = atomicAdd(&lrow[w >> 24], 1);  // LDS atomic
        g.csr_src[pos] = (int)(w & 0xFFFFFFu);
    }
    if (b == 0 && tid == 0) g.rowptr[n] = e;
}

// ---------------- matmul: Hs[n,D](fp16) = (X[n,K] @ W[K,D]) * dinv ----------------
// Each thread computes 2 adjacent features; half2 stores, float2 W loads.
template<int K, int D>
__global__ void k_matmul_h(const float* __restrict__ X, const float* __restrict__ W,
                           const float* __restrict__ dinv, __half* __restrict__ H, int n) {
    constexpr int HD = D / 2;
    constexpr int NPB = 256 / HD;
    __shared__ float xs[NPB][K];
    int node0 = blockIdx.x * NPB;
    int lid = threadIdx.x;
    for (int idx = lid; idx < NPB * K; idx += 256) {
        int nn = idx / K, kk = idx % K;
        int gn = node0 + nn;
        xs[nn][kk] = (gn < n) ? X[(size_t)gn * K + kk] : 0.0f;
    }
    __syncthreads();
    int g = lid / HD, f = lid % HD;
    int node = node0 + g;
    if (node >= n) return;
    float ax = 0.0f, ay = 0.0f;
    const float2* Wp = (const float2*)W;
#pragma unroll
    for (int k = 0; k < K; ++k) {
        float xv = xs[g][k];
        float2 w = Wp[k * HD + f];
        ax = fmaf(xv, w.x, ax);
        ay = fmaf(xv, w.y, ay);
    }
    float dv = dinv[node];
    ((__half2*)H)[(size_t)node * HD + f] = __floats2half2_rn(ax * dv, ay * dv);
}

// ---------------- layer-1 gather (fp16 rows, half2, 4x unroll) + fused layer-2 matmul ----------------
__global__ void k_gather_fuse(const int* __restrict__ rowptr, const int* __restrict__ csr_src,
                              const __half* __restrict__ Hs, const float* __restrict__ dinv,
                              const float* __restrict__ b1, const float* __restrict__ W2,
                              __half* __restrict__ H2, int n) {
    __shared__ float sh[8][HID];       // 2 KB
    __shared__ float w2s[HID][OUTD];   // 8 KB
    int tid = threadIdx.x;
    for (int i = tid; i < HID * OUTD; i += 256) w2s[i / OUTD][i % OUTD] = W2[i];
    int f2 = tid & 31, gi = tid >> 5;  // 32 lanes per node, 8 nodes per block
    int node = blockIdx.x * 8 + gi;
    float ax = 0.0f, ay = 0.0f;
    if (node < n) {
        const __half2* H = (const __half2*)Hs;
        float2 v = __half22float2(H[(size_t)node * (HID / 2) + f2]);  // self-loop
        ax = v.x; ay = v.y;
        int lo = rowptr[node], hi = rowptr[node + 1];
        int j = lo;
        for (; j + 4 <= hi; j += 4) {
            int s0 = csr_src[j], s1 = csr_src[j + 1], s2 = csr_src[j + 2], s3 = csr_src[j + 3];
            float2 v0 = __half22float2(H[(size_t)s0 * (HID / 2) + f2]);
            float2 v1 = __half22float2(H[(size_t)s1 * (HID / 2) + f2]);
            float2 v2 = __half22float2(H[(size_t)s2 * (HID / 2) + f2]);
            float2 v3 = __half22float2(H[(size_t)s3 * (HID / 2) + f2]);
            ax += (v0.x + v1.x) + (v2.x + v3.x);
            ay += (v0.y + v1.y) + (v2.y + v3.y);
        }
        for (; j < hi; ++j) {
            float2 v0 = __half22float2(H[(size_t)csr_src[j] * (HID / 2) + f2]);
            ax += v0.x; ay += v0.y;
        }
        float dv = dinv[node];
        float2 bb = ((const float2*)b1)[f2];
        ax = fmaxf(fmaf(ax, dv, bb.x), 0.0f);
        ay = fmaxf(fmaf(ay, dv, bb.y), 0.0f);
    }
    ((float2*)&sh[gi][0])[f2] = make_float2(ax, ay);
    __syncthreads();
    // layer-2 matmul: 8 nodes x 32 out-features = 256 threads
    int g2 = tid >> 5, fo = tid & 31;
    int node2 = blockIdx.x * 8 + g2;
    if (node2 < n) {
        float a2 = 0.0f;
#pragma unroll
        for (int k = 0; k < HID; ++k) a2 = fmaf(sh[g2][k], w2s[k][fo], a2);
        H2[(size_t)node2 * OUTD + fo] = __float2half(a2 * dinv[node2]);
    }
}

// ---------------- layer-2 gather (fp16 rows, half2, 4x unroll) ----------------
__global__ void k_gather2(const int* __restrict__ rowptr, const int* __restrict__ csr_src,
                          const __half* __restrict__ H2, const float* __restrict__ dinv,
                          float* __restrict__ out, int n) {
    int tid = threadIdx.x;
    int f2 = tid & 15, gi = tid >> 4;  // 16 lanes per node, 16 nodes per block
    int node = blockIdx.x * 16 + gi;
    if (node >= n) return;
    const __half2* H = (const __half2*)H2;
    float2 v = __half22float2(H[(size_t)node * (OUTD / 2) + f2]);  // self-loop
    float ax = v.x, ay = v.y;
    int lo = rowptr[node], hi = rowptr[node + 1];
    int j = lo;
    for (; j + 4 <= hi; j += 4) {
        int s0 = csr_src[j], s1 = csr_src[j + 1], s2 = csr_src[j + 2], s3 = csr_src[j + 3];
        float2 v0 = __half22float2(H[(size_t)s0 * (OUTD / 2) + f2]);
        float2 v1 = __half22float2(H[(size_t)s1 * (OUTD / 2) + f2]);
        float2 v2 = __half22float2(H[(size_t)s2 * (OUTD / 2) + f2]);
        float2 v3 = __half22float2(H[(size_t)s3 * (OUTD / 2) + f2]);
        ax += (v0.x + v1.x) + (v2.x + v3.x);
        ay += (v0.y + v1.y) + (v2.y + v3.y);
    }
    for (; j < hi; ++j) {
        float2 v0 = __half22float2(H[(size_t)csr_src[j] * (OUTD / 2) + f2]);
        ax += v0.x; ay += v0.y;
    }
    float dv = dinv[node];
    ((float2*)out)[(size_t)node * (OUTD / 2) + f2] = make_float2(ax * dv, ay * dv);
}

// ---------------- column z-score ----------------

__global__ void k_stats(GB g0, GB g1, int n) {
    const GB& g = blockIdx.y ? g1 : g0;
    int tid = threadIdx.x;
    int c = tid & 31;
    double s = 0.0, q = 0.0;
    long total = (long)n * OUTD;
    for (long t = (long)blockIdx.x * blockDim.x + tid; t < total;
         t += (long)gridDim.x * blockDim.x) {
        double v = (double)g.og[t];
        s += v; q += v * v;
    }
    __shared__ double ls[256], lq[256];
    ls[tid] = s; lq[tid] = q;
    __syncthreads();
    if (tid < 32) {
        for (int j = 32; j < 256; j += 32) { s += ls[tid + j]; q += lq[tid + j]; }
        atomicAdd(&g.st[c], s);
        atomicAdd(&g.st[c + 32], q);
    }
}

__global__ void k_finalize(GB g0, GB g1, int n) {
    const GB& g = blockIdx.y ? g1 : g0;
    int c = threadIdx.x;
    if (c < 32) {
        double sum = g.st[c], sq = g.st[c + 32];
        double mean = sum / (double)n;
        double var = (sq - sum * sum / (double)n) / (double)(n - 1);
        g.mr[c] = (float)mean;
        g.mr[c + 32] = (float)(1.0 / sqrt(var));
    }
}

__global__ void k_transform(GB g0, GB g1, int n) {
    const GB& g = blockIdx.y ? g1 : g0;
    int t = blockIdx.x * 256 + threadIdx.x;
    if (t < n * OUTD) {
        int c = t & 31;
        g.og[t] = (g.og[t] - g.mr[c]) * g.mr[c + 32];
    }
}

// ---------------- launch ----------------

extern "C" void kernel_launch(void* const* d_in, const int* in_sizes, int n_in,
                              void* d_out, int out_size, void* d_ws, size_t ws_size,
                              hipStream_t stream) {
    const float* x1 = (const float*)d_in[0];
    const int*   ei1 = (const int*)d_in[1];
    const float* x2 = (const float*)d_in[2];
    const int*   ei2 = (const int*)d_in[3];
    const float* W1 = (const float*)d_in[4];
    const float* b1 = (const float*)d_in[5];
    const float* W2 = (const float*)d_in[6];
    const float* b2 = (const float*)d_in[7];
    (void)b2;  // column-constant shift cancels exactly in the z-score
    (void)n_in; (void)out_size; (void)ws_size;

    int n = in_sizes[0] / IN_DIM;    // 50000
    int e = in_sizes[1] / 2;         // 800000
    float* out = (float*)d_out;
    int nb  = (n + BSZ - 1) >> BSH;  // 196 buckets
    int nbh = (e + EPB - 1) / EPB;   // 196 edge blocks

    char* ws = (char*)d_ws;
    size_t off = 0;
    auto alloc = [&](size_t bytes) {
        void* p = ws + off;
        off = (off + bytes + 255) & ~(size_t)255;
        return p;
    };
    int*    bh_base   = (int*)alloc((size_t)2 * nbh * nb * 4);
    int*    btot_base = (int*)alloc((size_t)2 * nb * 4);
    int*    boff_base = (int*)alloc((size_t)2 * nb * 4);
    double* st_base   = (double*)alloc(2 * 64 * 8);

    GB G[2];
    for (int g = 0; g < 2; ++g) {
        const int* ei = g ? ei2 : ei1;
        G[g].src  = ei;
        G[g].dst  = ei + e;
        G[g].bh   = bh_base + (size_t)g * nbh * nb;
        G[g].btot = btot_base + (size_t)g * nb;
        G[g].boff = boff_base + (size_t)g * nb;
        G[g].st   = st_base + (size_t)g * 64;
        G[g].rowptr  = (int*)alloc(((size_t)n + 1) * 4);
        G[g].csr_src = (int*)alloc((size_t)e * 4);
        G[g].dinv    = (float*)alloc((size_t)n * 4);
        G[g].mr      = (float*)alloc(64 * 4);
        G[g].og      = out + (size_t)g * n * OUTD;
    }
    // union region: pairs (build phase) aliases hs+h2 (compute phase, fp16)
    size_t pairs_bytes = (size_t)2 * e * 4;
    size_t dense_bytes = (size_t)n * HID * 2 + (size_t)n * OUTD * 2;
    char* uni = (char*)alloc(pairs_bytes > dense_bytes ? pairs_bytes : dense_bytes);
    G[0].pairs = (unsigned int*)uni;
    G[1].pairs = G[0].pairs + e;
    __half* hs = (__half*)uni;
    __half* h2 = (__half*)(uni + (size_t)n * HID * 2);

    // atomic-free bucketed CSR build, both graphs fused
    k_hist<<<dim3(nbh, 2), 256, 0, stream>>>(G[0], G[1], e, nb);
    k_colscan<<<dim3(nb, 2), 256, 0, stream>>>(G[0], G[1], nb, nbh);
    k_scan_btot<<<dim3(1, 2), 1024, 0, stream>>>(G[0], G[1], nb);
    k_part2<<<dim3(nbh, 2), 256, 0, stream>>>(G[0], G[1], e, nb);
    k_local_csr<<<dim3(nb, 2), BSZ, 0, stream>>>(G[0], G[1], n, e);

    // per-graph compute (hs/h2 shared across graphs -> serialize)
    for (int g = 0; g < 2; ++g) {
        const float* x = g ? x2 : x1;
        k_matmul_h<IN_DIM, HID><<<(n + 7) / 8, 256, 0, stream>>>(x, W1, G[g].dinv, hs, n);
        k_gather_fuse<<<(n + 7) / 8, 256, 0, stream>>>(G[g].rowptr, G[g].csr_src, hs,
                                                       G[g].dinv, b1, W2, h2, n);
        k_gather2<<<(n + 15) / 16, 256, 0, stream>>>(G[g].rowptr, G[g].csr_src, h2,
                                                     G[g].dinv, G[g].og, n);
    }

    // fused z-score for both graphs (st zeroed in k_scan_btot)
    k_stats<<<dim3(512, 2), 256, 0, stream>>>(G[0], G[1], n);
    k_finalize<<<dim3(1, 2), 32, 0, stream>>>(G[0], G[1], n);
    k_transform<<<dim3((n * OUTD + 255) / 256, 2), 256, 0, stream>>>(G[0], G[1], n);
}

// Round 7
// 187.479 us; speedup vs baseline: 4.9122x; 1.8662x over previous
//
#include <hip/hip_runtime.h>
#include <hip/hip_fp16.h>
#include <math.h>

#define IN_DIM 128
#define HID 64
#define OUTD 32
#define BSH 8            // log2 nodes per bucket
#define BSZ 256          // nodes per bucket == threads per local-CSR block
#define EPB 4096         // edges per histogram/partition block
#define XPAD 136         // 128 + 8 fp16 pad -> row stride 272B (17x16B, odd slot count)

typedef __attribute__((ext_vector_type(8))) _Float16 f16x8;
typedef __attribute__((ext_vector_type(4))) float f32x4;

// Per-graph pointer bundle for kernels fused across both graphs (blockIdx.y).
struct GB {
    const int* src; const int* dst;
    int* bh;               // [nbh][nb]: per-block bucket counts -> excl-in-bucket offsets
    int* btot;             // [nb] bucket totals
    int* boff;             // [nb] bucket base offsets (exclusive scan of btot)
    unsigned int* pairs;   // bucket-partitioned edges: src | (local_dst << 24)
    int* rowptr; int* csr_src;
    float* dinv;
    double* st; float* mr; float* og;
};

// ---------------- stage 1: per-block LDS histogram, dense output ----------------
__global__ void k_hist(GB g0, GB g1, int e, int nb) {
    const GB& g = blockIdx.y ? g1 : g0;
    __shared__ int hist[512];
    int tid = threadIdx.x;
    for (int i = tid; i < nb; i += 256) hist[i] = 0;
    __syncthreads();
    int base = blockIdx.x * EPB;
#pragma unroll
    for (int k = 0; k < EPB / 256; ++k) {
        int idx = base + k * 256 + tid;
        if (idx < e) atomicAdd(&hist[g.dst[idx] >> BSH], 1);  // LDS atomic
    }
    __syncthreads();
    int* row = g.bh + (size_t)blockIdx.x * nb;
    for (int i = tid; i < nb; i += 256) row[i] = hist[i];
}

// ---------------- stage 2: per-bucket column scan ----------------
__global__ void k_colscan(GB g0, GB g1, int nb, int nbh) {
    const GB& g = blockIdx.y ? g1 : g0;
    __shared__ int ls[256];
    int tid = threadIdx.x;
    int b = blockIdx.x;
    int v = (tid < nbh) ? g.bh[(size_t)tid * nb + b] : 0;
    ls[tid] = v;
    __syncthreads();
    for (int off = 1; off < 256; off <<= 1) {
        int u = (tid >= off) ? ls[tid - off] : 0;
        __syncthreads();
        ls[tid] += u;
        __syncthreads();
    }
    if (tid < nbh) g.bh[(size_t)tid * nb + b] = ls[tid] - v;
    if (tid == 255) g.btot[b] = ls[255];
}

// ---------------- stage 3: cross-bucket scan + zero stats ----------------
__global__ void k_scan_btot(GB g0, GB g1, int nb) {
    const GB& g = blockIdx.y ? g1 : g0;
    __shared__ int ls[1024];
    int tid = threadIdx.x;
    int v = (tid < nb) ? g.btot[tid] : 0;
    ls[tid] = v;
    __syncthreads();
    for (int off = 1; off < 1024; off <<= 1) {
        int u = (tid >= off) ? ls[tid - off] : 0;
        __syncthreads();
        ls[tid] += u;
        __syncthreads();
    }
    if (tid < nb) g.boff[tid] = ls[tid] - v;
    if (tid < 64) g.st[tid] = 0.0;
}

// ---------------- stage 4: partition edges (LDS cursors only) ----------------
__global__ void k_part2(GB g0, GB g1, int e, int nb) {
    const GB& g = blockIdx.y ? g1 : g0;
    __shared__ int lcur[512];
    int tid = threadIdx.x;
    const int* row = g.bh + (size_t)blockIdx.x * nb;
    for (int i = tid; i < nb; i += 256) lcur[i] = g.boff[i] + row[i];
    __syncthreads();
    int base = blockIdx.x * EPB;
#pragma unroll
    for (int k = 0; k < EPB / 256; ++k) {
        int idx = base + k * 256 + tid;
        if (idx < e) {
            int s = g.src[idx], d = g.dst[idx];
            int pos = atomicAdd(&lcur[d >> BSH], 1);          // LDS atomic
            g.pairs[pos] = (unsigned int)s | ((unsigned int)(d & (BSZ - 1)) << 24);
        }
    }
}

// ---------------- stage 5: per-bucket local CSR ----------------
__global__ void k_local_csr(GB g0, GB g1, int n, int e) {
    const GB& g = blockIdx.y ? g1 : g0;
    __shared__ int ldeg[BSZ], lrow[BSZ];
    int tid = threadIdx.x;
    int b = blockIdx.x;
    int node0 = b << BSH;
    int lo = g.boff[b], hi = lo + g.btot[b];
    ldeg[tid] = 0;
    __syncthreads();
    for (int j = lo + tid; j < hi; j += 256)
        atomicAdd(&ldeg[g.pairs[j] >> 24], 1);
    __syncthreads();
    int d = ldeg[tid];
    lrow[tid] = d;
    __syncthreads();
    for (int off = 1; off < BSZ; off <<= 1) {
        int u = (tid >= off) ? lrow[tid - off] : 0;
        __syncthreads();
        lrow[tid] += u;
        __syncthreads();
    }
    int node = node0 + tid;
    if (node < n) {
        g.rowptr[node] = lo + lrow[tid] - d;
        g.dinv[node] = rsqrtf((float)(d + 1));   // +1 = self-loop
    }
    lrow[tid] = lo + lrow[tid] - d;
    __syncthreads();
    for (int j = lo + tid; j < hi; j += 256) {
        unsigned int w = g.pairs[j];
        int pos = atomicAdd(&lrow[w >> 24], 1);  // LDS atomic
        g.csr_src[pos] = (int)(w & 0xFFFFFFu);
    }
    if (b == 0 && tid == 0) g.rowptr[n] = e;
}

// ---------------- layer-1 matmul via f16 MFMA ----------------
// Hs[n,64](fp16) = (X[n,128] @ W1[128,64]) * dinv[node]
// Block: 256 thr = 4 waves, 64 nodes. Wave: 16 nodes x 64 feats, 4 N-tiles x 4 K-steps.
// Fragment layout (m89/m91-verified family): A/B lane -> (row/col = lane&15,
// k = (lane>>4)*8 + j); C/D -> (col = lane&15, row = (lane>>4)*4 + reg).
__global__ void __launch_bounds__(256)
k_matmul_mfma(const float* __restrict__ X, const float* __restrict__ W,
              const float* __restrict__ dinv, _Float16* __restrict__ H, int n) {
    __shared__ _Float16 xs[64][XPAD];  // X tile, fp16
    __shared__ _Float16 wt[64][XPAD];  // W1^T [d][k], fp16
    int tid = threadIdx.x;
    int node0 = blockIdx.x * 64;
    {   // stage W1^T (coalesced float4 reads; one-time scattered LDS writes)
        const float4* W4 = (const float4*)W;   // W[128][64]
#pragma unroll
        for (int j = 0; j < 8; ++j) {
            int idx4 = tid + 256 * j;          // 2048 float4
            float4 w = W4[idx4];
            int k = idx4 >> 4;                 // 16 float4 per K-row
            int d = (idx4 & 15) * 4;
            wt[d][k]     = (_Float16)w.x;
            wt[d + 1][k] = (_Float16)w.y;
            wt[d + 2][k] = (_Float16)w.z;
            wt[d + 3][k] = (_Float16)w.w;
        }
    }
    {   // stage X tile (fp32 -> fp16), coalesced float4 reads
        const float4* X4 = (const float4*)X;
#pragma unroll
        for (int j = 0; j < 8; ++j) {
            int i = tid + 256 * j;             // 2048 float4
            int row = i >> 5, c4 = i & 31;
            int gn = node0 + row;
            float4 v = (gn < n) ? X4[(size_t)gn * 32 + c4] : make_float4(0.f, 0.f, 0.f, 0.f);
            _Float16* p = &xs[row][c4 * 4];
            p[0] = (_Float16)v.x; p[1] = (_Float16)v.y;
            p[2] = (_Float16)v.z; p[3] = (_Float16)v.w;
        }
    }
    __syncthreads();
    int wv = tid >> 6, lane = tid & 63;
    int r16 = lane & 15, khi = lane >> 4;      // khi in 0..3
    int wnode0 = wv * 16;
    f32x4 acc[4] = {};                         // 4 N-tiles of 16 feats
#pragma unroll
    for (int kk = 0; kk < 4; ++kk) {
        f16x8 a = *(const f16x8*)&xs[wnode0 + r16][kk * 32 + khi * 8];
#pragma unroll
        for (int nt = 0; nt < 4; ++nt) {
            f16x8 b = *(const f16x8*)&wt[nt * 16 + r16][kk * 32 + khi * 8];
            acc[nt] = __builtin_amdgcn_mfma_f32_16x16x32_f16(a, b, acc[nt], 0, 0, 0);
        }
    }
#pragma unroll
    for (int r = 0; r < 4; ++r) {
        int node = node0 + wnode0 + khi * 4 + r;
        if (node < n) {
            float dv = dinv[node];
#pragma unroll
            for (int nt = 0; nt < 4; ++nt)
                H[(size_t)node * HID + nt * 16 + r16] = (_Float16)(acc[nt][r] * dv);
        }
    }
}

// ---------------- layer-1 gather (fp16 rows, half2, 4x unroll) + fused layer-2 matmul ----------------
__global__ void k_gather_fuse(const int* __restrict__ rowptr, const int* __restrict__ csr_src,
                              const __half* __restrict__ Hs, const float* __restrict__ dinv,
                              const float* __restrict__ b1, const float* __restrict__ W2,
                              __half* __restrict__ H2, int n) {
    __shared__ float sh[8][HID];       // 2 KB
    __shared__ float w2s[HID][OUTD];   // 8 KB
    int tid = threadIdx.x;
    for (int i = tid; i < HID * OUTD; i += 256) w2s[i / OUTD][i % OUTD] = W2[i];
    int f2 = tid & 31, gi = tid >> 5;  // 32 lanes per node, 8 nodes per block
    int node = blockIdx.x * 8 + gi;
    float ax = 0.0f, ay = 0.0f;
    if (node < n) {
        const __half2* H = (const __half2*)Hs;
        float2 v = __half22float2(H[(size_t)node * (HID / 2) + f2]);  // self-loop
        ax = v.x; ay = v.y;
        int lo = rowptr[node], hi = rowptr[node + 1];
        int j = lo;
        for (; j + 4 <= hi; j += 4) {
            int s0 = csr_src[j], s1 = csr_src[j + 1], s2 = csr_src[j + 2], s3 = csr_src[j + 3];
            float2 v0 = __half22float2(H[(size_t)s0 * (HID / 2) + f2]);
            float2 v1 = __half22float2(H[(size_t)s1 * (HID / 2) + f2]);
            float2 v2 = __half22float2(H[(size_t)s2 * (HID / 2) + f2]);
            float2 v3 = __half22float2(H[(size_t)s3 * (HID / 2) + f2]);
            ax += (v0.x + v1.x) + (v2.x + v3.x);
            ay += (v0.y + v1.y) + (v2.y + v3.y);
        }
        for (; j < hi; ++j) {
            float2 v0 = __half22float2(H[(size_t)csr_src[j] * (HID / 2) + f2]);
            ax += v0.x; ay += v0.y;
        }
        float dv = dinv[node];
        float2 bb = ((const float2*)b1)[f2];
        ax = fmaxf(fmaf(ax, dv, bb.x), 0.0f);
        ay = fmaxf(fmaf(ay, dv, bb.y), 0.0f);
    }
    ((float2*)&sh[gi][0])[f2] = make_float2(ax, ay);
    __syncthreads();
    // layer-2 matmul: 8 nodes x 32 out-features = 256 threads
    int g2 = tid >> 5, fo = tid & 31;
    int node2 = blockIdx.x * 8 + g2;
    if (node2 < n) {
        float a2 = 0.0f;
#pragma unroll
        for (int k = 0; k < HID; ++k) a2 = fmaf(sh[g2][k], w2s[k][fo], a2);
        H2[(size_t)node2 * OUTD + fo] = __float2half(a2 * dinv[node2]);
    }
}

// ---------------- layer-2 gather (fp16 rows, half2, 4x unroll) ----------------
__global__ void k_gather2(const int* __restrict__ rowptr, const int* __restrict__ csr_src,
                          const __half* __restrict__ H2, const float* __restrict__ dinv,
                          float* __restrict__ out, int n) {
    int tid = threadIdx.x;
    int f2 = tid & 15, gi = tid >> 4;  // 16 lanes per node, 16 nodes per block
    int node = blockIdx.x * 16 + gi;
    if (node >= n) return;
    const __half2* H = (const __half2*)H2;
    float2 v = __half22float2(H[(size_t)node * (OUTD / 2) + f2]);  // self-loop
    float ax = v.x, ay = v.y;
    int lo = rowptr[node], hi = rowptr[node + 1];
    int j = lo;
    for (; j + 4 <= hi; j += 4) {
        int s0 = csr_src[j], s1 = csr_src[j + 1], s2 = csr_src[j + 2], s3 = csr_src[j + 3];
        float2 v0 = __half22float2(H[(size_t)s0 * (OUTD / 2) + f2]);
        float2 v1 = __half22float2(H[(size_t)s1 * (OUTD / 2) + f2]);
        float2 v2 = __half22float2(H[(size_t)s2 * (OUTD / 2) + f2]);
        float2 v3 = __half22float2(H[(size_t)s3 * (OUTD / 2) + f2]);
        ax += (v0.x + v1.x) + (v2.x + v3.x);
        ay += (v0.y + v1.y) + (v2.y + v3.y);
    }
    for (; j < hi; ++j) {
        float2 v0 = __half22float2(H[(size_t)csr_src[j] * (OUTD / 2) + f2]);
        ax += v0.x; ay += v0.y;
    }
    float dv = dinv[node];
    ((float2*)out)[(size_t)node * (OUTD / 2) + f2] = make_float2(ax * dv, ay * dv);
}

// ---------------- column z-score ----------------

__global__ void k_stats(GB g0, GB g1, int n) {
    const GB& g = blockIdx.y ? g1 : g0;
    int tid = threadIdx.x;
    int c = tid & 31;
    double s = 0.0, q = 0.0;
    long total = (long)n * OUTD;
    for (long t = (long)blockIdx.x * blockDim.x + tid; t < total;
         t += (long)gridDim.x * blockDim.x) {
        double v = (double)g.og[t];
        s += v; q += v * v;
    }
    __shared__ double ls[256], lq[256];
    ls[tid] = s; lq[tid] = q;
    __syncthreads();
    if (tid < 32) {
        for (int j = 32; j < 256; j += 32) { s += ls[tid + j]; q += lq[tid + j]; }
        atomicAdd(&g.st[c], s);
        atomicAdd(&g.st[c + 32], q);
    }
}

__global__ void k_finalize(GB g0, GB g1, int n) {
    const GB& g = blockIdx.y ? g1 : g0;
    int c = threadIdx.x;
    if (c < 32) {
        double sum = g.st[c], sq = g.st[c + 32];
        double mean = sum / (double)n;
        double var = (sq - sum * sum / (double)n) / (double)(n - 1);
        g.mr[c] = (float)mean;
        g.mr[c + 32] = (float)(1.0 / sqrt(var));
    }
}

__global__ void k_transform(GB g0, GB g1, int n) {
    const GB& g = blockIdx.y ? g1 : g0;
    int t = blockIdx.x * 256 + threadIdx.x;
    if (t < n * OUTD) {
        int c = t & 31;
        g.og[t] = (g.og[t] - g.mr[c]) * g.mr[c + 32];
    }
}

// ---------------- launch ----------------

extern "C" void kernel_launch(void* const* d_in, const int* in_sizes, int n_in,
                              void* d_out, int out_size, void* d_ws, size_t ws_size,
                              hipStream_t stream) {
    const float* x1 = (const float*)d_in[0];
    const int*   ei1 = (const int*)d_in[1];
    const float* x2 = (const float*)d_in[2];
    const int*   ei2 = (const int*)d_in[3];
    const float* W1 = (const float*)d_in[4];
    const float* b1 = (const float*)d_in[5];
    const float* W2 = (const float*)d_in[6];
    const float* b2 = (const float*)d_in[7];
    (void)b2;  // column-constant shift cancels exactly in the z-score
    (void)n_in; (void)out_size; (void)ws_size;

    int n = in_sizes[0] / IN_DIM;    // 50000
    int e = in_sizes[1] / 2;         // 800000
    float* out = (float*)d_out;
    int nb  = (n + BSZ - 1) >> BSH;  // 196 buckets
    int nbh = (e + EPB - 1) / EPB;   // 196 edge blocks

    char* ws = (char*)d_ws;
    size_t off = 0;
    auto alloc = [&](size_t bytes) {
        void* p = ws + off;
        off = (off + bytes + 255) & ~(size_t)255;
        return p;
    };
    int*    bh_base   = (int*)alloc((size_t)2 * nbh * nb * 4);
    int*    btot_base = (int*)alloc((size_t)2 * nb * 4);
    int*    boff_base = (int*)alloc((size_t)2 * nb * 4);
    double* st_base   = (double*)alloc(2 * 64 * 8);

    GB G[2];
    for (int g = 0; g < 2; ++g) {
        const int* ei = g ? ei2 : ei1;
        G[g].src  = ei;
        G[g].dst  = ei + e;
        G[g].bh   = bh_base + (size_t)g * nbh * nb;
        G[g].btot = btot_base + (size_t)g * nb;
        G[g].boff = boff_base + (size_t)g * nb;
        G[g].st   = st_base + (size_t)g * 64;
        G[g].rowptr  = (int*)alloc(((size_t)n + 1) * 4);
        G[g].csr_src = (int*)alloc((size_t)e * 4);
        G[g].dinv    = (float*)alloc((size_t)n * 4);
        G[g].mr      = (float*)alloc(64 * 4);
        G[g].og      = out + (size_t)g * n * OUTD;
    }
    // union region: pairs (build phase) aliases hs+h2 (compute phase, fp16)
    size_t pairs_bytes = (size_t)2 * e * 4;
    size_t dense_bytes = (size_t)n * HID * 2 + (size_t)n * OUTD * 2;
    char* uni = (char*)alloc(pairs_bytes > dense_bytes ? pairs_bytes : dense_bytes);
    G[0].pairs = (unsigned int*)uni;
    G[1].pairs = G[0].pairs + e;
    __half* hs = (__half*)uni;
    __half* h2 = (__half*)(uni + (size_t)n * HID * 2);

    // atomic-free bucketed CSR build, both graphs fused
    k_hist<<<dim3(nbh, 2), 256, 0, stream>>>(G[0], G[1], e, nb);
    k_colscan<<<dim3(nb, 2), 256, 0, stream>>>(G[0], G[1], nb, nbh);
    k_scan_btot<<<dim3(1, 2), 1024, 0, stream>>>(G[0], G[1], nb);
    k_part2<<<dim3(nbh, 2), 256, 0, stream>>>(G[0], G[1], e, nb);
    k_local_csr<<<dim3(nb, 2), BSZ, 0, stream>>>(G[0], G[1], n, e);

    // per-graph compute (hs/h2 shared across graphs -> serialize)
    for (int g = 0; g < 2; ++g) {
        const float* x = g ? x2 : x1;
        k_matmul_mfma<<<(n + 63) / 64, 256, 0, stream>>>(x, W1, G[g].dinv, (_Float16*)hs, n);
        k_gather_fuse<<<(n + 7) / 8, 256, 0, stream>>>(G[g].rowptr, G[g].csr_src, hs,
                                                       G[g].dinv, b1, W2, h2, n);
        k_gather2<<<(n + 15) / 16, 256, 0, stream>>>(G[g].rowptr, G[g].csr_src, h2,
                                                     G[g].dinv, G[g].og, n);
    }

    // fused z-score for both graphs (st zeroed in k_scan_btot)
    k_stats<<<dim3(512, 2), 256, 0, stream>>>(G[0], G[1], n);
    k_finalize<<<dim3(1, 2), 32, 0, stream>>>(G[0], G[1], n);
    k_transform<<<dim3((n * OUTD + 255) / 256, 2), 256, 0, stream>>>(G[0], G[1], n);
}

// Round 8
// 177.445 us; speedup vs baseline: 5.1900x; 1.0565x over previous
//
#include <hip/hip_runtime.h>
#include <hip/hip_fp16.h>
#include <math.h>

#define IN_DIM 128
#define HID 64
#define OUTD 32
#define BSH 8            // log2 nodes per bucket
#define BSZ 256          // nodes per bucket == threads per local-CSR block
#define EPB 4096         // edges per histogram/partition block
#define XPAD 136         // 128 + 8 fp16 pad

typedef __attribute__((ext_vector_type(8))) _Float16 f16x8;
typedef __attribute__((ext_vector_type(4))) float f32x4;

// Per-graph pointer bundle.
struct GB {
    const int* src; const int* dst;
    int* bh;               // [nbh][nb]: per-block bucket counts -> excl-in-bucket offsets
    int* btot;             // [nb] bucket totals
    int* boff;             // [nb] bucket base offsets
    unsigned int* pairs;   // bucket-partitioned edges: src | (local_dst << 24)
    int* rowptr; int* csr_src;
    float* dinv;
    double* st; float* og;
    const float* x;        // input features
    _Float16* hs;          // layer-1 matmul output, UNSCALED, fp16
    __half* h2;            // layer-2 matmul output, prescaled by dinv, fp16
};

// ---------------- phase 1 (fused): edge-bucket histogram + layer-1 MFMA matmul ----------------
// blocks [0, 2*nbh): histogram; blocks [2*nbh, 2*nbh+2*nmm): matmul.
// Matmul is independent of the CSR chain (hs unscaled), so both underfilling
// phases share one launch and fill the GPU together.
__global__ void __launch_bounds__(256) k_p1(GB g0, GB g1, const float* __restrict__ W,
                                            int e, int n, int nb, int nbh, int nmm) {
    __shared__ char smem[2 * 64 * XPAD * 2];  // 34.8 KB union
    int tid = threadIdx.x;
    int bx = blockIdx.x;
    if (bx < 2 * nbh) {
        // ---- histogram role ----
        const GB& g = (bx >= nbh) ? g1 : g0;
        int blk = (bx >= nbh) ? bx - nbh : bx;
        int* hist = (int*)smem;
        for (int i = tid; i < nb; i += 256) hist[i] = 0;
        __syncthreads();
        int base = blk * EPB;
#pragma unroll
        for (int k = 0; k < EPB / 256; ++k) {
            int idx = base + k * 256 + tid;
            if (idx < e) atomicAdd(&hist[g.dst[idx] >> BSH], 1);  // LDS atomic
        }
        __syncthreads();
        int* row = g.bh + (size_t)blk * nb;
        for (int i = tid; i < nb; i += 256) row[i] = hist[i];
    } else {
        // ---- MFMA matmul role: hs[n,64](fp16) = X[n,128] @ W1[128,64] (unscaled) ----
        int mx = bx - 2 * nbh;
        const GB& g = (mx >= nmm) ? g1 : g0;
        int blk = (mx >= nmm) ? mx - nmm : mx;
        _Float16 (*xs)[XPAD] = (_Float16(*)[XPAD])smem;
        _Float16 (*wt)[XPAD] = (_Float16(*)[XPAD])(smem + 64 * XPAD * 2);
        int node0 = blk * 64;
        {   // stage W1^T
            const float4* W4 = (const float4*)W;
#pragma unroll
            for (int j = 0; j < 8; ++j) {
                int idx4 = tid + 256 * j;
                float4 w = W4[idx4];
                int k = idx4 >> 4;
                int d = (idx4 & 15) * 4;
                wt[d][k]     = (_Float16)w.x;
                wt[d + 1][k] = (_Float16)w.y;
                wt[d + 2][k] = (_Float16)w.z;
                wt[d + 3][k] = (_Float16)w.w;
            }
        }
        {   // stage X tile
            const float4* X4 = (const float4*)g.x;
#pragma unroll
            for (int j = 0; j < 8; ++j) {
                int i = tid + 256 * j;
                int row = i >> 5, c4 = i & 31;
                int gn = node0 + row;
                float4 v = (gn < n) ? X4[(size_t)gn * 32 + c4] : make_float4(0.f, 0.f, 0.f, 0.f);
                _Float16* p = &xs[row][c4 * 4];
                p[0] = (_Float16)v.x; p[1] = (_Float16)v.y;
                p[2] = (_Float16)v.z; p[3] = (_Float16)v.w;
            }
        }
        __syncthreads();
        int wv = tid >> 6, lane = tid & 63;
        int r16 = lane & 15, khi = lane >> 4;
        int wnode0 = wv * 16;
        f32x4 acc[4] = {};
#pragma unroll
        for (int kk = 0; kk < 4; ++kk) {
            f16x8 a = *(const f16x8*)&xs[wnode0 + r16][kk * 32 + khi * 8];
#pragma unroll
            for (int nt = 0; nt < 4; ++nt) {
                f16x8 b = *(const f16x8*)&wt[nt * 16 + r16][kk * 32 + khi * 8];
                acc[nt] = __builtin_amdgcn_mfma_f32_16x16x32_f16(a, b, acc[nt], 0, 0, 0);
            }
        }
#pragma unroll
        for (int r = 0; r < 4; ++r) {
            int node = node0 + wnode0 + khi * 4 + r;
            if (node < n) {
#pragma unroll
                for (int nt = 0; nt < 4; ++nt)
                    g.hs[(size_t)node * HID + nt * 16 + r16] = (_Float16)acc[nt][r];
            }
        }
    }
}

// ---------------- stage 2: per-bucket column scan ----------------
__global__ void k_colscan(GB g0, GB g1, int nb, int nbh) {
    const GB& g = blockIdx.y ? g1 : g0;
    __shared__ int ls[256];
    int tid = threadIdx.x;
    int b = blockIdx.x;
    int v = (tid < nbh) ? g.bh[(size_t)tid * nb + b] : 0;
    ls[tid] = v;
    __syncthreads();
    for (int off = 1; off < 256; off <<= 1) {
        int u = (tid >= off) ? ls[tid - off] : 0;
        __syncthreads();
        ls[tid] += u;
        __syncthreads();
    }
    if (tid < nbh) g.bh[(size_t)tid * nb + b] = ls[tid] - v;
    if (tid == 255) g.btot[b] = ls[255];
}

// ---------------- stage 3: cross-bucket scan + zero stats ----------------
__global__ void k_scan_btot(GB g0, GB g1, int nb) {
    const GB& g = blockIdx.y ? g1 : g0;
    __shared__ int ls[1024];
    int tid = threadIdx.x;
    int v = (tid < nb) ? g.btot[tid] : 0;
    ls[tid] = v;
    __syncthreads();
    for (int off = 1; off < 1024; off <<= 1) {
        int u = (tid >= off) ? ls[tid - off] : 0;
        __syncthreads();
        ls[tid] += u;
        __syncthreads();
    }
    if (tid < nb) g.boff[tid] = ls[tid] - v;
    if (tid < 64) g.st[tid] = 0.0;
}

// ---------------- stage 4: partition edges (LDS cursors only) ----------------
__global__ void k_part2(GB g0, GB g1, int e, int nb) {
    const GB& g = blockIdx.y ? g1 : g0;
    __shared__ int lcur[512];
    int tid = threadIdx.x;
    const int* row = g.bh + (size_t)blockIdx.x * nb;
    for (int i = tid; i < nb; i += 256) lcur[i] = g.boff[i] + row[i];
    __syncthreads();
    int base = blockIdx.x * EPB;
#pragma unroll
    for (int k = 0; k < EPB / 256; ++k) {
        int idx = base + k * 256 + tid;
        if (idx < e) {
            int s = g.src[idx], d = g.dst[idx];
            int pos = atomicAdd(&lcur[d >> BSH], 1);          // LDS atomic
            g.pairs[pos] = (unsigned int)s | ((unsigned int)(d & (BSZ - 1)) << 24);
        }
    }
}

// ---------------- stage 5: per-bucket local CSR ----------------
__global__ void k_local_csr(GB g0, GB g1, int n, int e) {
    const GB& g = blockIdx.y ? g1 : g0;
    __shared__ int ldeg[BSZ], lrow[BSZ];
    int tid = threadIdx.x;
    int b = blockIdx.x;
    int node0 = b << BSH;
    int lo = g.boff[b], hi = lo + g.btot[b];
    ldeg[tid] = 0;
    __syncthreads();
    for (int j = lo + tid; j < hi; j += 256)
        atomicAdd(&ldeg[g.pairs[j] >> 24], 1);
    __syncthreads();
    int d = ldeg[tid];
    lrow[tid] = d;
    __syncthreads();
    for (int off = 1; off < BSZ; off <<= 1) {
        int u = (tid >= off) ? lrow[tid - off] : 0;
        __syncthreads();
        lrow[tid] += u;
        __syncthreads();
    }
    int node = node0 + tid;
    if (node < n) {
        g.rowptr[node] = lo + lrow[tid] - d;
        g.dinv[node] = rsqrtf((float)(d + 1));   // +1 = self-loop
    }
    lrow[tid] = lo + lrow[tid] - d;
    __syncthreads();
    for (int j = lo + tid; j < hi; j += 256) {
        unsigned int w = g.pairs[j];
        int pos = atomicAdd(&lrow[w >> 24], 1);  // LDS atomic
        g.csr_src[pos] = (int)(w & 0xFFFFFFu);
    }
    if (b == 0 && tid == 0) g.rowptr[n] = e;
}

// ---------------- layer-1 gather (unscaled hs; per-edge dinv[s]) + fused layer-2 matmul ----------------
__global__ void k_gather_fuse(const int* __restrict__ rowptr, const int* __restrict__ csr_src,
                              const __half* __restrict__ Hs, const float* __restrict__ dinv,
                              const float* __restrict__ b1, const float* __restrict__ W2,
                              __half* __restrict__ H2, int n) {
    __shared__ float sh[8][HID];       // 2 KB
    __shared__ float w2s[HID][OUTD];   // 8 KB
    int tid = threadIdx.x;
    for (int i = tid; i < HID * OUTD; i += 256) w2s[i / OUTD][i % OUTD] = W2[i];
    int f2 = tid & 31, gi = tid >> 5;  // 32 lanes per node, 8 nodes per block
    int node = blockIdx.x * 8 + gi;
    float ax = 0.0f, ay = 0.0f;
    float dv = 0.0f;
    if (node < n) {
        dv = dinv[node];
        const __half2* H = (const __half2*)Hs;
        float2 v = __half22float2(H[(size_t)node * (HID / 2) + f2]);  // self-loop (unscaled)
        ax = v.x * dv; ay = v.y * dv;
        int lo = rowptr[node], hi = rowptr[node + 1];
        int j = lo;
        for (; j + 4 <= hi; j += 4) {
            int s0 = csr_src[j], s1 = csr_src[j + 1], s2 = csr_src[j + 2], s3 = csr_src[j + 3];
            float d0 = dinv[s0], d1 = dinv[s1], d2 = dinv[s2], d3 = dinv[s3];
            float2 v0 = __half22float2(H[(size_t)s0 * (HID / 2) + f2]);
            float2 v1 = __half22float2(H[(size_t)s1 * (HID / 2) + f2]);
            float2 v2 = __half22float2(H[(size_t)s2 * (HID / 2) + f2]);
            float2 v3 = __half22float2(H[(size_t)s3 * (HID / 2) + f2]);
            ax = fmaf(v0.x, d0, fmaf(v1.x, d1, fmaf(v2.x, d2, fmaf(v3.x, d3, ax))));
            ay = fmaf(v0.y, d0, fmaf(v1.y, d1, fmaf(v2.y, d2, fmaf(v3.y, d3, ay))));
        }
        for (; j < hi; ++j) {
            int s0 = csr_src[j];
            float d0 = dinv[s0];
            float2 v0 = __half22float2(H[(size_t)s0 * (HID / 2) + f2]);
            ax = fmaf(v0.x, d0, ax); ay = fmaf(v0.y, d0, ay);
        }
        float2 bb = ((const float2*)b1)[f2];
        ax = fmaxf(fmaf(ax, dv, bb.x), 0.0f);
        ay = fmaxf(fmaf(ay, dv, bb.y), 0.0f);
    }
    ((float2*)&sh[gi][0])[f2] = make_float2(ax, ay);
    __syncthreads();
    // layer-2 matmul: 8 nodes x 32 out-features = 256 threads; prescale by dinv
    int g2 = tid >> 5, fo = tid & 31;
    int node2 = blockIdx.x * 8 + g2;
    if (node2 < n) {
        float a2 = 0.0f;
#pragma unroll
        for (int k = 0; k < HID; ++k) a2 = fmaf(sh[g2][k], w2s[k][fo], a2);
        H2[(size_t)node2 * OUTD + fo] = __float2half(a2 * dinv[node2]);
    }
}

// ---------------- layer-2 gather (h2 prescaled) ----------------
__global__ void k_gather2(const int* __restrict__ rowptr, const int* __restrict__ csr_src,
                          const __half* __restrict__ H2, const float* __restrict__ dinv,
                          float* __restrict__ out, int n) {
    int tid = threadIdx.x;
    int f2 = tid & 15, gi = tid >> 4;  // 16 lanes per node, 16 nodes per block
    int node = blockIdx.x * 16 + gi;
    if (node >= n) return;
    const __half2* H = (const __half2*)H2;
    float2 v = __half22float2(H[(size_t)node * (OUTD / 2) + f2]);  // self-loop
    float ax = v.x, ay = v.y;
    int lo = rowptr[node], hi = rowptr[node + 1];
    int j = lo;
    for (; j + 4 <= hi; j += 4) {
        int s0 = csr_src[j], s1 = csr_src[j + 1], s2 = csr_src[j + 2], s3 = csr_src[j + 3];
        float2 v0 = __half22float2(H[(size_t)s0 * (OUTD / 2) + f2]);
        float2 v1 = __half22float2(H[(size_t)s1 * (OUTD / 2) + f2]);
        float2 v2 = __half22float2(H[(size_t)s2 * (OUTD / 2) + f2]);
        float2 v3 = __half22float2(H[(size_t)s3 * (OUTD / 2) + f2]);
        ax += (v0.x + v1.x) + (v2.x + v3.x);
        ay += (v0.y + v1.y) + (v2.y + v3.y);
    }
    for (; j < hi; ++j) {
        float2 v0 = __half22float2(H[(size_t)csr_src[j] * (OUTD / 2) + f2]);
        ax += v0.x; ay += v0.y;
    }
    float dv = dinv[node];
    ((float2*)out)[(size_t)node * (OUTD / 2) + f2] = make_float2(ax * dv, ay * dv);
}

// ---------------- column z-score ----------------

__global__ void k_stats(GB g0, GB g1, int n) {
    const GB& g = blockIdx.y ? g1 : g0;
    int tid = threadIdx.x;
    int c = tid & 31;
    double s = 0.0, q = 0.0;
    long total = (long)n * OUTD;
    for (long t = (long)blockIdx.x * blockDim.x + tid; t < total;
         t += (long)gridDim.x * blockDim.x) {
        double v = (double)g.og[t];
        s += v; q += v * v;
    }
    __shared__ double ls[256], lq[256];
    ls[tid] = s; lq[tid] = q;
    __syncthreads();
    if (tid < 32) {
        for (int j = 32; j < 256; j += 32) { s += ls[tid + j]; q += lq[tid + j]; }
        atomicAdd(&g.st[c], s);
        atomicAdd(&g.st[c + 32], q);
    }
}

// transform with finalize folded in (mean/rstd recomputed per block from st)
__global__ void k_transform(GB g0, GB g1, int n) {
    const GB& g = blockIdx.y ? g1 : g0;
    __shared__ float fm[32], fr[32];
    int tid = threadIdx.x;
    if (tid < 32) {
        double sum = g.st[tid], sq = g.st[tid + 32];
        double mean = sum / (double)n;
        double var = (sq - sum * sum / (double)n) / (double)(n - 1);
        fm[tid] = (float)mean;
        fr[tid] = (float)(1.0 / sqrt(var));
    }
    __syncthreads();
    int t = blockIdx.x * 256 + tid;
    if (t < n * OUTD) {
        int c = t & 31;
        g.og[t] = (g.og[t] - fm[c]) * fr[c];
    }
}

// ---------------- launch ----------------

extern "C" void kernel_launch(void* const* d_in, const int* in_sizes, int n_in,
                              void* d_out, int out_size, void* d_ws, size_t ws_size,
                              hipStream_t stream) {
    const float* x1 = (const float*)d_in[0];
    const int*   ei1 = (const int*)d_in[1];
    const float* x2 = (const float*)d_in[2];
    const int*   ei2 = (const int*)d_in[3];
    const float* W1 = (const float*)d_in[4];
    const float* b1 = (const float*)d_in[5];
    const float* W2 = (const float*)d_in[6];
    const float* b2 = (const float*)d_in[7];
    (void)b2;  // column-constant shift cancels exactly in the z-score
    (void)n_in; (void)out_size; (void)ws_size;

    int n = in_sizes[0] / IN_DIM;    // 50000
    int e = in_sizes[1] / 2;         // 800000
    float* out = (float*)d_out;
    int nb  = (n + BSZ - 1) >> BSH;  // 196 buckets
    int nbh = (e + EPB - 1) / EPB;   // 196 edge blocks
    int nmm = (n + 63) / 64;         // 782 matmul blocks

    char* ws = (char*)d_ws;
    size_t off = 0;
    auto alloc = [&](size_t bytes) {
        void* p = ws + off;
        off = (off + bytes + 255) & ~(size_t)255;
        return p;
    };
    int*    bh_base   = (int*)alloc((size_t)2 * nbh * nb * 4);
    int*    btot_base = (int*)alloc((size_t)2 * nb * 4);
    int*    boff_base = (int*)alloc((size_t)2 * nb * 4);
    double* st_base   = (double*)alloc(2 * 64 * 8);

    GB G[2];
    for (int g = 0; g < 2; ++g) {
        const int* ei = g ? ei2 : ei1;
        G[g].src  = ei;
        G[g].dst  = ei + e;
        G[g].x    = g ? x2 : x1;
        G[g].bh   = bh_base + (size_t)g * nbh * nb;
        G[g].btot = btot_base + (size_t)g * nb;
        G[g].boff = boff_base + (size_t)g * nb;
        G[g].st   = st_base + (size_t)g * 64;
        G[g].rowptr  = (int*)alloc(((size_t)n + 1) * 4);
        G[g].csr_src = (int*)alloc((size_t)e * 4);
        G[g].dinv    = (float*)alloc((size_t)n * 4);
        G[g].og      = out + (size_t)g * n * OUTD;
        G[g].hs      = (_Float16*)alloc((size_t)n * HID * 2);  // live from k_p1 on
    }
    // pairs (dead after local_csr) aliases h2 buffers (live from gather_fuse on)
    size_t pairs_bytes = (size_t)2 * e * 4;
    size_t h2_bytes    = (size_t)2 * n * OUTD * 2;
    char* uni = (char*)alloc(pairs_bytes > h2_bytes ? pairs_bytes : h2_bytes);
    G[0].pairs = (unsigned int*)uni;
    G[1].pairs = G[0].pairs + e;
    G[0].h2 = (__half*)uni;
    G[1].h2 = G[0].h2 + (size_t)n * OUTD;

    // phase 1: histogram (both graphs) + MFMA matmul (both graphs) in ONE launch
    k_p1<<<dim3(2 * nbh + 2 * nmm), 256, 0, stream>>>(G[0], G[1], W1, e, n, nb, nbh, nmm);
    // CSR chain
    k_colscan<<<dim3(nb, 2), 256, 0, stream>>>(G[0], G[1], nb, nbh);
    k_scan_btot<<<dim3(1, 2), 1024, 0, stream>>>(G[0], G[1], nb);
    k_part2<<<dim3(nbh, 2), 256, 0, stream>>>(G[0], G[1], e, nb);
    k_local_csr<<<dim3(nb, 2), BSZ, 0, stream>>>(G[0], G[1], n, e);

    // per-graph gathers (serialized to keep the random-read working set L2-sized)
    for (int g = 0; g < 2; ++g) {
        k_gather_fuse<<<(n + 7) / 8, 256, 0, stream>>>(G[g].rowptr, G[g].csr_src,
                                                       (const __half*)G[g].hs,
                                                       G[g].dinv, b1, W2, G[g].h2, n);
        k_gather2<<<(n + 15) / 16, 256, 0, stream>>>(G[g].rowptr, G[g].csr_src, G[g].h2,
                                                     G[g].dinv, G[g].og, n);
    }

    // fused z-score for both graphs (st zeroed in k_scan_btot)
    k_stats<<<dim3(512, 2), 256, 0, stream>>>(G[0], G[1], n);
    k_transform<<<dim3((n * OUTD + 255) / 256, 2), 256, 0, stream>>>(G[0], G[1], n);
}

// Round 9
// 150.694 us; speedup vs baseline: 6.1113x; 1.1775x over previous
//
#include <hip/hip_runtime.h>
#include <hip/hip_fp16.h>
#include <math.h>

#define IN_DIM 128
#define HID 64
#define OUTD 32
#define BSH 8            // log2 nodes per bucket
#define BSZ 256          // nodes per bucket == threads per local-CSR block
#define EPB 4096         // edges per histogram/partition block
#define XPAD 136         // 128 + 8 fp16 pad
#define NCOPY 16         // spread copies of the stats accumulators

typedef __attribute__((ext_vector_type(8))) _Float16 f16x8;
typedef __attribute__((ext_vector_type(4))) float f32x4;

// Per-graph pointer bundle.
struct GB {
    const int* src; const int* dst;
    int* bh;               // [nbh][nb]: per-block bucket counts -> excl-in-bucket offsets
    int* btot;             // [nb] bucket totals
    int* boff;             // [nb] bucket base offsets
    unsigned int* pairs;   // bucket-partitioned edges: src | (local_dst << 24)
    int* rowptr; int* csr_src;
    float* dinv;
    double* st;            // [NCOPY][64] spread stats accumulators
    float* og;
    const float* x;        // input features
    _Float16* hs;          // layer-1 matmul output, UNSCALED, fp16
    __half* h2;            // layer-2 matmul output, prescaled by dinv, fp16
};

// ---------------- phase 1 (fused): edge-bucket histogram + layer-1 MFMA matmul ----------------
__global__ void __launch_bounds__(256) k_p1(GB g0, GB g1, const float* __restrict__ W,
                                            int e, int n, int nb, int nbh, int nmm) {
    __shared__ char smem[2 * 64 * XPAD * 2];  // 34.8 KB union
    int tid = threadIdx.x;
    int bx = blockIdx.x;
    if (bx < 2 * nbh) {
        // ---- histogram role ----
        const GB& g = (bx >= nbh) ? g1 : g0;
        int blk = (bx >= nbh) ? bx - nbh : bx;
        int* hist = (int*)smem;
        for (int i = tid; i < nb; i += 256) hist[i] = 0;
        __syncthreads();
        int base = blk * EPB;
#pragma unroll
        for (int k = 0; k < EPB / 256; ++k) {
            int idx = base + k * 256 + tid;
            if (idx < e) atomicAdd(&hist[g.dst[idx] >> BSH], 1);  // LDS atomic
        }
        __syncthreads();
        int* row = g.bh + (size_t)blk * nb;
        for (int i = tid; i < nb; i += 256) row[i] = hist[i];
    } else {
        // ---- MFMA matmul role: hs[n,64](fp16) = X[n,128] @ W1[128,64] (unscaled) ----
        int mx = bx - 2 * nbh;
        const GB& g = (mx >= nmm) ? g1 : g0;
        int blk = (mx >= nmm) ? mx - nmm : mx;
        _Float16 (*xs)[XPAD] = (_Float16(*)[XPAD])smem;
        _Float16 (*wt)[XPAD] = (_Float16(*)[XPAD])(smem + 64 * XPAD * 2);
        int node0 = blk * 64;
        {   // stage W1^T
            const float4* W4 = (const float4*)W;
#pragma unroll
            for (int j = 0; j < 8; ++j) {
                int idx4 = tid + 256 * j;
                float4 w = W4[idx4];
                int k = idx4 >> 4;
                int d = (idx4 & 15) * 4;
                wt[d][k]     = (_Float16)w.x;
                wt[d + 1][k] = (_Float16)w.y;
                wt[d + 2][k] = (_Float16)w.z;
                wt[d + 3][k] = (_Float16)w.w;
            }
        }
        {   // stage X tile
            const float4* X4 = (const float4*)g.x;
#pragma unroll
            for (int j = 0; j < 8; ++j) {
                int i = tid + 256 * j;
                int row = i >> 5, c4 = i & 31;
                int gn = node0 + row;
                float4 v = (gn < n) ? X4[(size_t)gn * 32 + c4] : make_float4(0.f, 0.f, 0.f, 0.f);
                _Float16* p = &xs[row][c4 * 4];
                p[0] = (_Float16)v.x; p[1] = (_Float16)v.y;
                p[2] = (_Float16)v.z; p[3] = (_Float16)v.w;
            }
        }
        __syncthreads();
        int wv = tid >> 6, lane = tid & 63;
        int r16 = lane & 15, khi = lane >> 4;
        int wnode0 = wv * 16;
        f32x4 acc[4] = {};
#pragma unroll
        for (int kk = 0; kk < 4; ++kk) {
            f16x8 a = *(const f16x8*)&xs[wnode0 + r16][kk * 32 + khi * 8];
#pragma unroll
            for (int nt = 0; nt < 4; ++nt) {
                f16x8 b = *(const f16x8*)&wt[nt * 16 + r16][kk * 32 + khi * 8];
                acc[nt] = __builtin_amdgcn_mfma_f32_16x16x32_f16(a, b, acc[nt], 0, 0, 0);
            }
        }
#pragma unroll
        for (int r = 0; r < 4; ++r) {
            int node = node0 + wnode0 + khi * 4 + r;
            if (node < n) {
#pragma unroll
                for (int nt = 0; nt < 4; ++nt)
                    g.hs[(size_t)node * HID + nt * 16 + r16] = (_Float16)acc[nt][r];
            }
        }
    }
}

// ---------------- stage 2: per-bucket column scan ----------------
__global__ void k_colscan(GB g0, GB g1, int nb, int nbh) {
    const GB& g = blockIdx.y ? g1 : g0;
    __shared__ int ls[256];
    int tid = threadIdx.x;
    int b = blockIdx.x;
    int v = (tid < nbh) ? g.bh[(size_t)tid * nb + b] : 0;
    ls[tid] = v;
    __syncthreads();
    for (int off = 1; off < 256; off <<= 1) {
        int u = (tid >= off) ? ls[tid - off] : 0;
        __syncthreads();
        ls[tid] += u;
        __syncthreads();
    }
    if (tid < nbh) g.bh[(size_t)tid * nb + b] = ls[tid] - v;
    if (tid == 255) g.btot[b] = ls[255];
}

// ---------------- stage 3: cross-bucket scan + zero stats copies ----------------
__global__ void k_scan_btot(GB g0, GB g1, int nb) {
    const GB& g = blockIdx.y ? g1 : g0;
    __shared__ int ls[1024];
    int tid = threadIdx.x;
    int v = (tid < nb) ? g.btot[tid] : 0;
    ls[tid] = v;
    __syncthreads();
    for (int off = 1; off < 1024; off <<= 1) {
        int u = (tid >= off) ? ls[tid - off] : 0;
        __syncthreads();
        ls[tid] += u;
        __syncthreads();
    }
    if (tid < nb) g.boff[tid] = ls[tid] - v;
    g.st[tid] = 0.0;  // NCOPY*64 == 1024
}

// ---------------- stage 4: partition edges (LDS cursors only) ----------------
__global__ void k_part2(GB g0, GB g1, int e, int nb) {
    const GB& g = blockIdx.y ? g1 : g0;
    __shared__ int lcur[512];
    int tid = threadIdx.x;
    const int* row = g.bh + (size_t)blockIdx.x * nb;
    for (int i = tid; i < nb; i += 256) lcur[i] = g.boff[i] + row[i];
    __syncthreads();
    int base = blockIdx.x * EPB;
#pragma unroll
    for (int k = 0; k < EPB / 256; ++k) {
        int idx = base + k * 256 + tid;
        if (idx < e) {
            int s = g.src[idx], d = g.dst[idx];
            int pos = atomicAdd(&lcur[d >> BSH], 1);          // LDS atomic
            g.pairs[pos] = (unsigned int)s | ((unsigned int)(d & (BSZ - 1)) << 24);
        }
    }
}

// ---------------- stage 5: per-bucket local CSR ----------------
__global__ void k_local_csr(GB g0, GB g1, int n, int e) {
    const GB& g = blockIdx.y ? g1 : g0;
    __shared__ int ldeg[BSZ], lrow[BSZ];
    int tid = threadIdx.x;
    int b = blockIdx.x;
    int node0 = b << BSH;
    int lo = g.boff[b], hi = lo + g.btot[b];
    ldeg[tid] = 0;
    __syncthreads();
    for (int j = lo + tid; j < hi; j += 256)
        atomicAdd(&ldeg[g.pairs[j] >> 24], 1);
    __syncthreads();
    int d = ldeg[tid];
    lrow[tid] = d;
    __syncthreads();
    for (int off = 1; off < BSZ; off <<= 1) {
        int u = (tid >= off) ? lrow[tid - off] : 0;
        __syncthreads();
        lrow[tid] += u;
        __syncthreads();
    }
    int node = node0 + tid;
    if (node < n) {
        g.rowptr[node] = lo + lrow[tid] - d;
        g.dinv[node] = rsqrtf((float)(d + 1));   // +1 = self-loop
    }
    lrow[tid] = lo + lrow[tid] - d;
    __syncthreads();
    for (int j = lo + tid; j < hi; j += 256) {
        unsigned int w = g.pairs[j];
        int pos = atomicAdd(&lrow[w >> 24], 1);  // LDS atomic
        g.csr_src[pos] = (int)(w & 0xFFFFFFu);
    }
    if (b == 0 && tid == 0) g.rowptr[n] = e;
}

// ---------------- layer-1 gather (both graphs; 8-wide MLP) + fused layer-2 matmul ----------------
__global__ void k_gather_fuse(GB g0, GB g1, const float* __restrict__ b1,
                              const float* __restrict__ W2, int n) {
    const GB& g = blockIdx.y ? g1 : g0;
    __shared__ float sh[8][HID];       // 2 KB
    __shared__ float w2s[HID][OUTD];   // 8 KB
    int tid = threadIdx.x;
    for (int i = tid; i < HID * OUTD; i += 256) w2s[i / OUTD][i % OUTD] = W2[i];
    int f2 = tid & 31, gi = tid >> 5;  // 32 lanes per node, 8 nodes per block
    int node = blockIdx.x * 8 + gi;
    float ax = 0.0f, ay = 0.0f;
    if (node < n) {
        float dv = g.dinv[node];
        const __half2* H = (const __half2*)g.hs;
        float2 v = __half22float2(H[(size_t)node * (HID / 2) + f2]);  // self-loop (unscaled)
        ax = v.x * dv; ay = v.y * dv;
        int lo = g.rowptr[node], hi = g.rowptr[node + 1];
        int j = lo;
        for (; j + 8 <= hi; j += 8) {
            int s[8]; float dd[8]; float2 vv[8];
#pragma unroll
            for (int u = 0; u < 8; ++u) s[u] = g.csr_src[j + u];
#pragma unroll
            for (int u = 0; u < 8; ++u) dd[u] = g.dinv[s[u]];
#pragma unroll
            for (int u = 0; u < 8; ++u) vv[u] = __half22float2(H[(size_t)s[u] * (HID / 2) + f2]);
#pragma unroll
            for (int u = 0; u < 8; ++u) { ax = fmaf(vv[u].x, dd[u], ax); ay = fmaf(vv[u].y, dd[u], ay); }
        }
        if (j + 4 <= hi) {
            int s[4]; float dd[4]; float2 vv[4];
#pragma unroll
            for (int u = 0; u < 4; ++u) s[u] = g.csr_src[j + u];
#pragma unroll
            for (int u = 0; u < 4; ++u) dd[u] = g.dinv[s[u]];
#pragma unroll
            for (int u = 0; u < 4; ++u) vv[u] = __half22float2(H[(size_t)s[u] * (HID / 2) + f2]);
#pragma unroll
            for (int u = 0; u < 4; ++u) { ax = fmaf(vv[u].x, dd[u], ax); ay = fmaf(vv[u].y, dd[u], ay); }
            j += 4;
        }
        for (; j < hi; ++j) {
            int s0 = g.csr_src[j];
            float d0 = g.dinv[s0];
            float2 v0 = __half22float2(H[(size_t)s0 * (HID / 2) + f2]);
            ax = fmaf(v0.x, d0, ax); ay = fmaf(v0.y, d0, ay);
        }
        float2 bb = ((const float2*)b1)[f2];
        ax = fmaxf(fmaf(ax, dv, bb.x), 0.0f);
        ay = fmaxf(fmaf(ay, dv, bb.y), 0.0f);
    }
    ((float2*)&sh[gi][0])[f2] = make_float2(ax, ay);
    __syncthreads();
    // layer-2 matmul: 8 nodes x 32 out-features = 256 threads; prescale by dinv
    int g2 = tid >> 5, fo = tid & 31;
    int node2 = blockIdx.x * 8 + g2;
    if (node2 < n) {
        float a2 = 0.0f;
#pragma unroll
        for (int k = 0; k < HID; ++k) a2 = fmaf(sh[g2][k], w2s[k][fo], a2);
        g.h2[(size_t)node2 * OUTD + fo] = __float2half(a2 * g.dinv[node2]);
    }
}

// ---------------- layer-2 gather (both graphs; 8-wide MLP) + fused column stats ----------------
__global__ void k_gather2s(GB g0, GB g1, int n) {
    const GB& g = blockIdx.y ? g1 : g0;
    __shared__ float sx[16][32], sq[16][32];
    int tid = threadIdx.x;
    int f2 = tid & 15, gi = tid >> 4;  // 16 lanes per node, 16 nodes per block
    int node = blockIdx.x * 16 + gi;
    float ax = 0.0f, ay = 0.0f;
    if (node < n) {
        const __half2* H = (const __half2*)g.h2;
        float2 v = __half22float2(H[(size_t)node * (OUTD / 2) + f2]);  // self-loop (prescaled)
        ax = v.x; ay = v.y;
        int lo = g.rowptr[node], hi = g.rowptr[node + 1];
        int j = lo;
        for (; j + 8 <= hi; j += 8) {
            int s[8]; float2 vv[8];
#pragma unroll
            for (int u = 0; u < 8; ++u) s[u] = g.csr_src[j + u];
#pragma unroll
            for (int u = 0; u < 8; ++u) vv[u] = __half22float2(H[(size_t)s[u] * (OUTD / 2) + f2]);
#pragma unroll
            for (int u = 0; u < 8; ++u) { ax += vv[u].x; ay += vv[u].y; }
        }
        if (j + 4 <= hi) {
            int s[4]; float2 vv[4];
#pragma unroll
            for (int u = 0; u < 4; ++u) s[u] = g.csr_src[j + u];
#pragma unroll
            for (int u = 0; u < 4; ++u) vv[u] = __half22float2(H[(size_t)s[u] * (OUTD / 2) + f2]);
#pragma unroll
            for (int u = 0; u < 4; ++u) { ax += vv[u].x; ay += vv[u].y; }
            j += 4;
        }
        for (; j < hi; ++j) {
            float2 v0 = __half22float2(H[(size_t)g.csr_src[j] * (OUTD / 2) + f2]);
            ax += v0.x; ay += v0.y;
        }
        float dv = g.dinv[node];
        ax *= dv; ay *= dv;
        ((float2*)g.og)[(size_t)node * (OUTD / 2) + f2] = make_float2(ax, ay);
    }
    // column partial sums (zeros for padding threads)
    sx[gi][2 * f2] = ax;        sx[gi][2 * f2 + 1] = ay;
    sq[gi][2 * f2] = ax * ax;   sq[gi][2 * f2 + 1] = ay * ay;
    __syncthreads();
    if (tid < 64) {
        int c = tid & 31;
        bool isq = tid >= 32;
        float s = 0.0f;
#pragma unroll
        for (int r = 0; r < 16; ++r) s += isq ? sq[r][c] : sx[r][c];
        atomicAdd(&g.st[(blockIdx.x & (NCOPY - 1)) * 64 + c + (isq ? 32 : 0)], (double)s);
    }
}

// ---------------- transform with finalize folded in (sums the NCOPY stat copies) ----------------
__global__ void k_transform(GB g0, GB g1, int n) {
    const GB& g = blockIdx.y ? g1 : g0;
    __shared__ float fm[32], fr[32];
    int tid = threadIdx.x;
    if (tid < 32) {
        double sum = 0.0, sqs = 0.0;
#pragma unroll
        for (int k = 0; k < NCOPY; ++k) {
            sum += g.st[k * 64 + tid];
            sqs += g.st[k * 64 + tid + 32];
        }
        double mean = sum / (double)n;
        double var = (sqs - sum * sum / (double)n) / (double)(n - 1);
        fm[tid] = (float)mean;
        fr[tid] = (float)(1.0 / sqrt(var));
    }
    __syncthreads();
    int t = blockIdx.x * 256 + tid;
    if (t < n * OUTD) {
        int c = t & 31;
        g.og[t] = (g.og[t] - fm[c]) * fr[c];
    }
}

// ---------------- launch ----------------

extern "C" void kernel_launch(void* const* d_in, const int* in_sizes, int n_in,
                              void* d_out, int out_size, void* d_ws, size_t ws_size,
                              hipStream_t stream) {
    const float* x1 = (const float*)d_in[0];
    const int*   ei1 = (const int*)d_in[1];
    const float* x2 = (const float*)d_in[2];
    const int*   ei2 = (const int*)d_in[3];
    const float* W1 = (const float*)d_in[4];
    const float* b1 = (const float*)d_in[5];
    const float* W2 = (const float*)d_in[6];
    const float* b2 = (const float*)d_in[7];
    (void)b2;  // column-constant shift cancels exactly in the z-score
    (void)n_in; (void)out_size; (void)ws_size;

    int n = in_sizes[0] / IN_DIM;    // 50000
    int e = in_sizes[1] / 2;         // 800000
    float* out = (float*)d_out;
    int nb  = (n + BSZ - 1) >> BSH;  // 196 buckets
    int nbh = (e + EPB - 1) / EPB;   // 196 edge blocks
    int nmm = (n + 63) / 64;         // 782 matmul blocks

    char* ws = (char*)d_ws;
    size_t off = 0;
    auto alloc = [&](size_t bytes) {
        void* p = ws + off;
        off = (off + bytes + 255) & ~(size_t)255;
        return p;
    };
    int*    bh_base   = (int*)alloc((size_t)2 * nbh * nb * 4);
    int*    btot_base = (int*)alloc((size_t)2 * nb * 4);
    int*    boff_base = (int*)alloc((size_t)2 * nb * 4);
    double* st_base   = (double*)alloc((size_t)2 * NCOPY * 64 * 8);

    GB G[2];
    for (int g = 0; g < 2; ++g) {
        const int* ei = g ? ei2 : ei1;
        G[g].src  = ei;
        G[g].dst  = ei + e;
        G[g].x    = g ? x2 : x1;
        G[g].bh   = bh_base + (size_t)g * nbh * nb;
        G[g].btot = btot_base + (size_t)g * nb;
        G[g].boff = boff_base + (size_t)g * nb;
        G[g].st   = st_base + (size_t)g * NCOPY * 64;
        G[g].rowptr  = (int*)alloc(((size_t)n + 1) * 4);
        G[g].csr_src = (int*)alloc((size_t)e * 4);
        G[g].dinv    = (float*)alloc((size_t)n * 4);
        G[g].og      = out + (size_t)g * n * OUTD;
        G[g].hs      = (_Float16*)alloc((size_t)n * HID * 2);  // live from k_p1 on
    }
    // pairs (dead after local_csr) aliases h2 buffers (live from gather_fuse on)
    size_t pairs_bytes = (size_t)2 * e * 4;
    size_t h2_bytes    = (size_t)2 * n * OUTD * 2;
    char* uni = (char*)alloc(pairs_bytes > h2_bytes ? pairs_bytes : h2_bytes);
    G[0].pairs = (unsigned int*)uni;
    G[1].pairs = G[0].pairs + e;
    G[0].h2 = (__half*)uni;
    G[1].h2 = G[0].h2 + (size_t)n * OUTD;

    // phase 1: histogram (both graphs) + MFMA matmul (both graphs) in ONE launch
    k_p1<<<dim3(2 * nbh + 2 * nmm), 256, 0, stream>>>(G[0], G[1], W1, e, n, nb, nbh, nmm);
    // CSR chain (both graphs per launch)
    k_colscan<<<dim3(nb, 2), 256, 0, stream>>>(G[0], G[1], nb, nbh);
    k_scan_btot<<<dim3(1, 2), 1024, 0, stream>>>(G[0], G[1], nb);
    k_part2<<<dim3(nbh, 2), 256, 0, stream>>>(G[0], G[1], e, nb);
    k_local_csr<<<dim3(nb, 2), BSZ, 0, stream>>>(G[0], G[1], n, e);

    // gathers, both graphs fused per launch
    k_gather_fuse<<<dim3((n + 7) / 8, 2), 256, 0, stream>>>(G[0], G[1], b1, W2, n);
    k_gather2s<<<dim3((n + 15) / 16, 2), 256, 0, stream>>>(G[0], G[1], n);

    // z-score transform (finalize folded; st zeroed in k_scan_btot)
    k_transform<<<dim3((n * OUTD + 255) / 256, 2), 256, 0, stream>>>(G[0], G[1], n);
}